// Round 3
// baseline (17086.011 us; speedup 1.0000x reference)
//
#include <hip/hip_runtime.h>
#include <hip/hip_bf16.h>
#include <math.h>

#define L_SEQ 4096
#define DM 512
#define DI 1024
#define DSTATE 16
#define NLAYERS 4
#define NC 8          // scan chunks
#define LC 512        // chunk length

typedef __bf16 v8bf __attribute__((ext_vector_type(8)));
typedef __bf16 v4bf __attribute__((ext_vector_type(4)));
typedef float  v4f  __attribute__((ext_vector_type(4)));

static __device__ __forceinline__ v4f mfma16(v8bf a, v8bf b, v4f c) {
  return __builtin_amdgcn_mfma_f32_16x16x32_bf16(a, b, c, 0, 0, 0);
}

// async global->LDS DMA, 16B per lane (lds dest must be wave-uniform; HW adds lane*16)
static __device__ __forceinline__ void lds_dma16(const void* g, void* l) {
  __builtin_amdgcn_global_load_lds(
      (const __attribute__((address_space(1))) void*)g,
      (__attribute__((address_space(3))) void*)l, 16, 0, 0);
}

// ---------------------------------------------------------------------------
// Packed hi/lo bf16 layout ("HL"): per row of K elems, kgroup g (8 elems) is
// 32 B: [16B hi bf16 x8][16B lo bf16 x8]. Row stride = K*4 bytes. A 16B "unit"
// u = g*2 + half. Same byte volume as fp32.
// ---------------------------------------------------------------------------
__global__ void pack_hl(const float* __restrict__ src, char* __restrict__ dst, int nunits) {
  int i = blockIdx.x * 256 + threadIdx.x;
  if (i >= nunits) return;
  const float4* s = reinterpret_cast<const float4*>(src) + (size_t)i * 2;
  float4 v0 = s[0], v1 = s[1];
  v8bf hi, lo;
  float f[8] = {v0.x, v0.y, v0.z, v0.w, v1.x, v1.y, v1.z, v1.w};
#pragma unroll
  for (int j = 0; j < 8; ++j) {
    hi[j] = (__bf16)f[j];
    lo[j] = (__bf16)(f[j] - (float)hi[j]);
  }
  *reinterpret_cast<v8bf*>(dst + (size_t)i * 32)      = hi;
  *reinterpret_cast<v8bf*>(dst + (size_t)i * 32 + 16) = lo;
}

// ---------------------------------------------------------------------------
// Embed: h[m][d] + packed h.  Thread = 8 consecutive d (one kgroup).
// ---------------------------------------------------------------------------
__global__ void embed_kernel(const float* __restrict__ x, const float* __restrict__ in_w,
                             const float* __restrict__ in_b, float* __restrict__ h,
                             char* __restrict__ h_pack, int b0, int Mc) {
  int idx = blockIdx.x * 256 + threadIdx.x;   // over Mc*64 kgroups
  int g = idx & 63;
  int m = idx >> 6;
  if (m >= Mc) return;
  int d0 = g * 8;
  int bg = b0 + (m >> 12);
  int l  = m & (L_SEQ - 1);
  const float* xp = x + ((size_t)bg * 3) * L_SEQ + l;
  float x0 = xp[0], x1 = xp[L_SEQ], x2 = xp[2 * L_SEQ];
  float f[8];
  v8bf hi, lo;
#pragma unroll
  for (int j = 0; j < 8; ++j) {
    int d = d0 + j;
    f[j] = in_b[d] + x0 * in_w[d*3+0] + x1 * in_w[d*3+1] + x2 * in_w[d*3+2];
    hi[j] = (__bf16)f[j];
    lo[j] = (__bf16)(f[j] - (float)hi[j]);
  }
  float* hp = h + (size_t)m * DM + d0;
  *reinterpret_cast<float4*>(hp)     = make_float4(f[0], f[1], f[2], f[3]);
  *reinterpret_cast<float4*>(hp + 4) = make_float4(f[4], f[5], f[6], f[7]);
  char* pp = h_pack + (size_t)m * (DM * 4) + g * 32;
  *reinterpret_cast<v8bf*>(pp)      = hi;
  *reinterpret_cast<v8bf*>(pp + 16) = lo;
}

// ---------------------------------------------------------------------------
// Split-bf16 3-pass MFMA GEMM on packed HL inputs.
// C[M][N] = A[M][K] * B[N][K]^T.  BM=128 BN=64 BK=64, 256 thr (4 waves),
// wave -> 32 rows x 64 cols.  Staging via global_load_lds width=16.
// LDS: no pad; unit u of row r stored at position u^(r&7) (XOR swizzle, done
// in the per-lane GLOBAL addresses so LDS-side DMA writes stay contiguous).
// ---------------------------------------------------------------------------
#define BM 128
#define BN 64
#define BK 64

__global__ __launch_bounds__(256) void gemm_pk3(
    const char* __restrict__ Ap, const char* __restrict__ Bp, float* __restrict__ C,
    int K, int ldc) {
  __shared__ __align__(16) char lds[49152];   // A: 32KB (2048 units), B: 16KB
  int tid = threadIdx.x;
  int w = tid >> 6, lane = tid & 63;
  int m0 = blockIdx.y * BM, n0 = blockIdx.x * BN;
  int Ku = K >> 2;                 // 16B units per row
  int lrow = lane & 15, lq = lane >> 4;
  int sw = lrow & 7;

  // per-lane global staging bases (swizzled unit index)
  const char* aBase[8];
  const char* bBase[4];
#pragma unroll
  for (int i = 0; i < 8; ++i) {
    int row = w * 32 + i * 4 + (lane >> 4);
    int uu  = (lane & 15) ^ (row & 7);
    aBase[i] = Ap + ((size_t)(m0 + row) * Ku + uu) * 16;
  }
#pragma unroll
  for (int i = 0; i < 4; ++i) {
    int row = w * 16 + i * 4 + (lane >> 4);
    int uu  = (lane & 15) ^ (row & 7);
    bBase[i] = Bp + ((size_t)(n0 + row) * Ku + uu) * 16;
  }
  char* aLdsW = lds + w * 8192;            // wave's A region (8 x 1KB insts)
  char* bLdsW = lds + 32768 + w * 4096;    // wave's B region (4 x 1KB insts)

  v4f acc[2][4];
#pragma unroll
  for (int i = 0; i < 2; ++i)
#pragma unroll
    for (int j = 0; j < 4; ++j)
#pragma unroll
      for (int e = 0; e < 4; ++e) acc[i][j][e] = 0.0f;

  size_t koff = 0;
  for (int k0 = 0; k0 < K; k0 += BK, koff += 256) {
    __syncthreads();   // previous-iter readers done before overwrite
#pragma unroll
    for (int i = 0; i < 8; ++i) lds_dma16(aBase[i] + koff, aLdsW + i * 1024);
#pragma unroll
    for (int i = 0; i < 4; ++i) lds_dma16(bBase[i] + koff, bLdsW + i * 1024);
    __syncthreads();   // vmcnt(0) drain -> tiles visible

#pragma unroll
    for (int kk = 0; kk < 2; ++kk) {
      int u2 = (kk * 4 + lq) * 2;
      int o_hi = ((u2    ) ^ sw) << 4;
      int o_lo = ((u2 + 1) ^ sw) << 4;
      v8bf aF[2][2], bF[4][2];
#pragma unroll
      for (int mt = 0; mt < 2; ++mt) {
        const char* pa = lds + (w * 32 + mt * 16 + lrow) * 256;
        aF[mt][0] = *reinterpret_cast<const v8bf*>(pa + o_hi);
        aF[mt][1] = *reinterpret_cast<const v8bf*>(pa + o_lo);
      }
#pragma unroll
      for (int nt = 0; nt < 4; ++nt) {
        const char* pb = lds + 32768 + (nt * 16 + lrow) * 256;
        bF[nt][0] = *reinterpret_cast<const v8bf*>(pb + o_hi);
        bF[nt][1] = *reinterpret_cast<const v8bf*>(pb + o_lo);
      }
#pragma unroll
      for (int mt = 0; mt < 2; ++mt)
#pragma unroll
        for (int nt = 0; nt < 4; ++nt) {
          acc[mt][nt] = mfma16(aF[mt][0], bF[nt][0], acc[mt][nt]);  // hi*hi
          acc[mt][nt] = mfma16(aF[mt][0], bF[nt][1], acc[mt][nt]);  // hi*lo
          acc[mt][nt] = mfma16(aF[mt][1], bF[nt][0], acc[mt][nt]);  // lo*hi
        }
    }
  }

  // C/D layout: col=lane&15, row=(lane>>4)*4+reg  [m89/m91-verified]
#pragma unroll
  for (int mt = 0; mt < 2; ++mt)
#pragma unroll
    for (int nt = 0; nt < 4; ++nt) {
      int rbase = m0 + w * 32 + mt * 16 + lq * 4;
      int cidx  = n0 + nt * 16 + lrow;
#pragma unroll
      for (int r = 0; r < 4; ++r)
        C[(size_t)(rbase + r) * ldc + cidx] = acc[mt][nt][r];
    }
}

// ---------------------------------------------------------------------------
// Depthwise causal conv (k=4) + bias + SiLU; writes u fp32 + packed u.
// Thread = one kgroup (8 d's).
// ---------------------------------------------------------------------------
__global__ void conv_silu_kernel(const float* __restrict__ xz, const float* __restrict__ cw,
                                 const float* __restrict__ cb, float* __restrict__ u,
                                 char* __restrict__ u_pack, int Mc) {
  int idx = blockIdx.x * 256 + threadIdx.x;   // over Mc*128 kgroups
  int g = idx & 127;
  int m = idx >> 7;
  if (m >= Mc) return;
  int d0 = g * 8;
  int t = m & (L_SEQ - 1);
  float r[8];
  {
    const float4* cbp = reinterpret_cast<const float4*>(cb + d0);
    float4 c0 = cbp[0], c1 = cbp[1];
    r[0]=c0.x; r[1]=c0.y; r[2]=c0.z; r[3]=c0.w; r[4]=c1.x; r[5]=c1.y; r[6]=c1.z; r[7]=c1.w;
  }
#pragma unroll
  for (int k = 0; k < 4; ++k) {
    if (t + k >= 3) {
      const float4* src = reinterpret_cast<const float4*>(xz + (size_t)(m + k - 3) * 2048 + d0);
      float4 v0 = src[0], v1 = src[1];
      float vv[8] = {v0.x, v0.y, v0.z, v0.w, v1.x, v1.y, v1.z, v1.w};
#pragma unroll
      for (int j = 0; j < 8; ++j) r[j] += vv[j] * cw[(d0 + j) * 4 + k];
    }
  }
  v8bf hi, lo;
#pragma unroll
  for (int j = 0; j < 8; ++j) {
    r[j] = r[j] / (1.0f + expf(-r[j]));
    hi[j] = (__bf16)r[j];
    lo[j] = (__bf16)(r[j] - (float)hi[j]);
  }
  float* up = u + (size_t)m * DI + d0;
  *reinterpret_cast<float4*>(up)     = make_float4(r[0], r[1], r[2], r[3]);
  *reinterpret_cast<float4*>(up + 4) = make_float4(r[4], r[5], r[6], r[7]);
  char* pp = u_pack + (size_t)m * (DI * 4) + g * 32;
  *reinterpret_cast<v8bf*>(pp)      = hi;
  *reinterpret_cast<v8bf*>(pp + 16) = lo;
}

// ---------------------------------------------------------------------------
// dt tile kernel: dt[m][d] = softplus(dbl[m][0:32].dtw[d][:] + dtb[d])
// ---------------------------------------------------------------------------
__global__ __launch_bounds__(256) void dt_tile(const float* __restrict__ dbl,
                                               const float* __restrict__ dtw,
                                               const float* __restrict__ dtb,
                                               float* __restrict__ dt) {
  __shared__ float s_a[64][33];
  __shared__ float s_w[64][33];
  int tid = threadIdx.x;
  int m0 = blockIdx.x * 64, d0 = blockIdx.y * 64;
#pragma unroll
  for (int i = 0; i < 8; ++i) {
    int idx = tid + i * 256;
    int r = idx >> 5, cc = idx & 31;
    s_a[r][cc] = dbl[(size_t)(m0 + r) * 64 + cc];
    s_w[r][cc] = dtw[(size_t)(d0 + r) * 32 + cc];
  }
  __syncthreads();
  int tm = tid >> 4, td = tid & 15;
  float acc[4][4];
#pragma unroll
  for (int i = 0; i < 4; ++i)
#pragma unroll
    for (int j = 0; j < 4; ++j) acc[i][j] = dtb[d0 + td + 16 * j];
#pragma unroll
  for (int k = 0; k < 32; ++k) {
    float a_[4], w_[4];
#pragma unroll
    for (int i = 0; i < 4; ++i) a_[i] = s_a[tm * 4 + i][k];
#pragma unroll
    for (int j = 0; j < 4; ++j) w_[j] = s_w[td + 16 * j][k];
#pragma unroll
    for (int i = 0; i < 4; ++i)
#pragma unroll
      for (int j = 0; j < 4; ++j) acc[i][j] += a_[i] * w_[j];
  }
#pragma unroll
  for (int i = 0; i < 4; ++i)
#pragma unroll
    for (int j = 0; j < 4; ++j) {
      float v = acc[i][j];
      float sp = (v > 15.0f) ? v : log1pf(expf(v));
      dt[(size_t)(m0 + tm * 4 + i) * DI + d0 + td + 16 * j] = sp;
    }
}

// ---------------------------------------------------------------------------
// Scan pass 1: per chunk from h=0, final state + decay product.
// ---------------------------------------------------------------------------
#define TT 16
__global__ __launch_bounds__(256) void scan_pass1(
    const float* __restrict__ dt, const float* __restrict__ u,
    const float* __restrict__ dbl, const float* __restrict__ Alog,
    float* __restrict__ cfF, float* __restrict__ cfP) {
  __shared__ __align__(16) float s_dt[TT][64];
  __shared__ __align__(16) float s_u [TT][64];
  __shared__ __align__(16) float s_b [TT][16];
  int tid = threadIdx.x;
  int d0 = blockIdx.x * 64;
  int c  = blockIdx.y;
  int bi = blockIdx.z;
  int dl = tid >> 2;
  int sg = (tid & 3) * 4;
  int d  = d0 + dl;
  float a2[4], h[4] = {0.f,0.f,0.f,0.f}, p[4] = {1.f,1.f,1.f,1.f};
#pragma unroll
  for (int j = 0; j < 4; ++j)
    a2[j] = -expf(Alog[(size_t)d * DSTATE + sg + j]) * 1.44269504088896340736f;
  size_t mbase = (size_t)bi * L_SEQ + (size_t)c * LC;
  int tr = tid >> 4, c4 = (tid & 15) * 4;

  for (int t0 = 0; t0 < LC; t0 += TT) {
    size_t m = mbase + t0 + tr;
    *reinterpret_cast<float4*>(&s_dt[tr][c4]) = *reinterpret_cast<const float4*>(dt + m*DI + d0 + c4);
    *reinterpret_cast<float4*>(&s_u [tr][c4]) = *reinterpret_cast<const float4*>(u  + m*DI + d0 + c4);
    if (tid < 64) {
      int tr3 = tid >> 2, cB = (tid & 3) * 4;
      *reinterpret_cast<float4*>(&s_b[tr3][cB]) =
          *reinterpret_cast<const float4*>(dbl + (mbase + t0 + tr3)*64 + 32 + cB);
    }
    __syncthreads();
#pragma unroll
    for (int t = 0; t < TT; ++t) {
      float dtv = s_dt[t][dl];
      float cu  = dtv * s_u[t][dl];
      float4 Bv = *reinterpret_cast<const float4*>(&s_b[t][sg]);
      float dA;
      dA = exp2f(dtv * a2[0]); h[0] = dA*h[0] + cu*Bv.x; p[0] *= dA;
      dA = exp2f(dtv * a2[1]); h[1] = dA*h[1] + cu*Bv.y; p[1] *= dA;
      dA = exp2f(dtv * a2[2]); h[2] = dA*h[2] + cu*Bv.z; p[2] *= dA;
      dA = exp2f(dtv * a2[3]); h[3] = dA*h[3] + cu*Bv.w; p[3] *= dA;
    }
    __syncthreads();
  }
  size_t cbase = (((size_t)bi * NC + c) * DI + d) * DSTATE + sg;
  *reinterpret_cast<float4*>(cfF + cbase) = make_float4(h[0],h[1],h[2],h[3]);
  *reinterpret_cast<float4*>(cfP + cbase) = make_float4(p[0],p[1],p[2],p[3]);
}

// ---------------------------------------------------------------------------
// Scan pass 2: serial prefix over chunks (final -> entry states), in place.
// ---------------------------------------------------------------------------
__global__ __launch_bounds__(256) void chunk_prefix(float* __restrict__ cfF,
                                                    const float* __restrict__ cfP,
                                                    int nb) {
  int gid = blockIdx.x * 256 + threadIdx.x;
  if (gid >= nb * DI) return;
  int bi = gid >> 10;
  int d  = gid & (DI - 1);
  float4 carry[4];
#pragma unroll
  for (int q = 0; q < 4; ++q) carry[q] = make_float4(0.f,0.f,0.f,0.f);
  size_t base = (((size_t)bi * NC) * DI + d) * DSTATE;
  const size_t cs = (size_t)DI * DSTATE;
  for (int c = 0; c < NC; ++c) {
    float4 f[4], p[4];
    if (c < NC - 1) {
#pragma unroll
      for (int q = 0; q < 4; ++q) {
        f[q] = *reinterpret_cast<const float4*>(cfF + base + c*cs + q*4);
        p[q] = *reinterpret_cast<const float4*>(cfP + base + c*cs + q*4);
      }
    }
#pragma unroll
    for (int q = 0; q < 4; ++q)
      *reinterpret_cast<float4*>(cfF + base + c*cs + q*4) = carry[q];
    if (c < NC - 1) {
#pragma unroll
      for (int q = 0; q < 4; ++q) {
        carry[q].x = p[q].x*carry[q].x + f[q].x;
        carry[q].y = p[q].y*carry[q].y + f[q].y;
        carry[q].z = p[q].z*carry[q].z + f[q].z;
        carry[q].w = p[q].w*carry[q].w + f[q].w;
      }
    }
  }
}

// ---------------------------------------------------------------------------
// Scan pass 3: full scan per chunk from entry state + gate; writes packed y.
// ---------------------------------------------------------------------------
__global__ __launch_bounds__(256) void scan_pass3(
    const float* __restrict__ dt, const float* __restrict__ u,
    const float* __restrict__ xz, const float* __restrict__ dbl,
    const float* __restrict__ Alog, const float* __restrict__ Dp,
    const float* __restrict__ cfF, char* __restrict__ y_pack) {
  __shared__ __align__(16) float s_dt[TT][64];
  __shared__ __align__(16) float s_u [TT][64];
  __shared__ __align__(16) float s_z [TT][64];
  __shared__ __align__(16) float s_bc[TT][32];
  __shared__ __align__(16) float s_y [TT][64];
  int tid = threadIdx.x;
  int d0 = blockIdx.x * 64;
  int c  = blockIdx.y;
  int bi = blockIdx.z;
  int dl = tid >> 2;
  int sg = (tid & 3) * 4;
  int d  = d0 + dl;
  float a2[4], hst[4];
  size_t cbase = (((size_t)bi * NC + c) * DI + d) * DSTATE + sg;
  float4 ent = *reinterpret_cast<const float4*>(cfF + cbase);
  hst[0]=ent.x; hst[1]=ent.y; hst[2]=ent.z; hst[3]=ent.w;
#pragma unroll
  for (int j = 0; j < 4; ++j)
    a2[j] = -expf(Alog[(size_t)d * DSTATE + sg + j]) * 1.44269504088896340736f;
  float dp = Dp[d];
  size_t mbase = (size_t)bi * L_SEQ + (size_t)c * LC;

  int tr = tid >> 4, c4 = (tid & 15) * 4;
  int tr2 = tid >> 3, c2 = (tid & 7) * 4;

  for (int t0 = 0; t0 < LC; t0 += TT) {
    size_t m = mbase + t0 + tr;
    *reinterpret_cast<float4*>(&s_dt[tr][c4]) = *reinterpret_cast<const float4*>(dt + m*DI + d0 + c4);
    *reinterpret_cast<float4*>(&s_u [tr][c4]) = *reinterpret_cast<const float4*>(u  + m*DI + d0 + c4);
    *reinterpret_cast<float4*>(&s_z [tr][c4]) = *reinterpret_cast<const float4*>(xz + m*2048 + DI + d0 + c4);
    if (tid < 128) {
      size_t m2 = mbase + t0 + tr2;
      *reinterpret_cast<float4*>(&s_bc[tr2][c2]) = *reinterpret_cast<const float4*>(dbl + m2*64 + 32 + c2);
    }
    __syncthreads();
#pragma unroll
    for (int t = 0; t < TT; ++t) {
      float dtv = s_dt[t][dl];
      float uv  = s_u[t][dl];
      float cu  = dtv * uv;
      float4 Bv = *reinterpret_cast<const float4*>(&s_bc[t][sg]);
      float4 Cv = *reinterpret_cast<const float4*>(&s_bc[t][16 + sg]);
      float yp = 0.0f;
      {
        float dA;
        dA = exp2f(dtv * a2[0]); hst[0] = dA*hst[0] + cu*Bv.x; yp += hst[0]*Cv.x;
        dA = exp2f(dtv * a2[1]); hst[1] = dA*hst[1] + cu*Bv.y; yp += hst[1]*Cv.y;
        dA = exp2f(dtv * a2[2]); hst[2] = dA*hst[2] + cu*Bv.z; yp += hst[2]*Cv.z;
        dA = exp2f(dtv * a2[3]); hst[3] = dA*hst[3] + cu*Bv.w; yp += hst[3]*Cv.w;
      }
      yp += __shfl_xor(yp, 1);
      yp += __shfl_xor(yp, 2);
      if ((tid & 3) == 0) {
        float zv = s_z[t][dl];
        s_y[t][dl] = (yp + uv * dp) * (zv / (1.0f + expf(-zv)));
      }
    }
    __syncthreads();
    {
      float4 v = *reinterpret_cast<float4*>(&s_y[tr][c4]);
      int k = d0 + c4;                       // multiple of 4
      v4bf hi, lo;
      float f[4] = {v.x, v.y, v.z, v.w};
#pragma unroll
      for (int j = 0; j < 4; ++j) {
        hi[j] = (__bf16)f[j];
        lo[j] = (__bf16)(f[j] - (float)hi[j]);
      }
      char* pp = y_pack + m * (DI * 4) + (k >> 3) * 32 + ((k & 4) << 1);
      *reinterpret_cast<v4bf*>(pp)      = hi;
      *reinterpret_cast<v4bf*>(pp + 16) = lo;
    }
    __syncthreads();
  }
}

// ---------------------------------------------------------------------------
// Pool
// ---------------------------------------------------------------------------
__global__ __launch_bounds__(512) void pool_kernel(const float* __restrict__ h,
                                                   float* __restrict__ pooled,
                                                   int b0) {
  int b = blockIdx.x >> 5;
  int chunk = blockIdx.x & 31;
  int d = threadIdx.x;
  float s = 0.0f;
  size_t base = (size_t)b * L_SEQ + chunk * 128;
  for (int l = 0; l < 128; ++l) s += h[(base + l) * DM + d];
  atomicAdd(pooled + (size_t)(b0 + b) * DM + d, s * (1.0f / 4096.0f));
}

// ---------------------------------------------------------------------------
// Head: LayerNorm + classifier
// ---------------------------------------------------------------------------
__global__ __launch_bounds__(512) void head_kernel(const float* __restrict__ pooled,
                                                   const float* __restrict__ nw,
                                                   const float* __restrict__ nbv,
                                                   const float* __restrict__ clw,
                                                   const float* __restrict__ clb,
                                                   float* __restrict__ out) {
  __shared__ float rs[8], rq[8];
  __shared__ float ln[512];
  int b = blockIdx.x, tid = threadIdx.x;
  int wid = tid >> 6, lane = tid & 63;
  float v = pooled[(size_t)b * DM + tid];
  float s = v, q = v * v;
#pragma unroll
  for (int off = 1; off < 64; off <<= 1) { s += __shfl_xor(s, off); q += __shfl_xor(q, off); }
  if (lane == 0) { rs[wid] = s; rq[wid] = q; }
  __syncthreads();
  if (tid == 0) {
    float S = 0, Q = 0;
    for (int i = 0; i < 8; ++i) { S += rs[i]; Q += rq[i]; }
    rs[0] = S; rq[0] = Q;
  }
  __syncthreads();
  float mu  = rs[0] / 512.0f;
  float var = rq[0] / 512.0f - mu * mu;
  ln[tid] = (v - mu) * rsqrtf(var + 1e-5f) * nw[tid] + nbv[tid];
  __syncthreads();
  if (tid < 320) {
    int c = tid >> 5, l2 = tid & 31;
    float p = 0.0f;
    for (int dd = l2; dd < 512; dd += 32) p += ln[dd] * clw[c * 512 + dd];
#pragma unroll
    for (int off = 1; off < 32; off <<= 1) p += __shfl_xor(p, off);
    if (l2 == 0) out[(size_t)b * 10 + c] = p + clb[c];
  }
}

// ---------------------------------------------------------------------------
extern "C" void kernel_launch(void* const* d_in, const int* in_sizes, int n_in,
                              void* d_out, int out_size, void* d_ws, size_t ws_size,
                              hipStream_t stream) {
  (void)in_sizes; (void)n_in; (void)out_size;
  const float* x    = (const float*)d_in[0];
  const float* in_w = (const float*)d_in[1];
  const float* in_b = (const float*)d_in[2];
  const float* ipw  = (const float*)d_in[3];
  const float* cw   = (const float*)d_in[4];
  const float* cb   = (const float*)d_in[5];
  const float* xpw  = (const float*)d_in[6];
  const float* dtw  = (const float*)d_in[7];
  const float* dtb  = (const float*)d_in[8];
  const float* Alog = (const float*)d_in[9];
  const float* Dp   = (const float*)d_in[10];
  const float* opw  = (const float*)d_in[11];
  const float* nw   = (const float*)d_in[12];
  const float* nbv  = (const float*)d_in[13];
  const float* clw  = (const float*)d_in[14];
  const float* clb  = (const float*)d_in[15];
  float* out = (float*)d_out;

  // per-token float-equivalents: h 512 + xz 2048 + u 1024 + dbl 64 + dt 1024
  //   + h_pack 512 + u_pack 1024 + y_pack 1024 = 7232
  const size_t per_m_bytes = 7232ull * 4ull;
  const size_t cf_per_b    = 2ull * NC * DI * DSTATE * 4ull;
  const size_t wpack_bytes = (size_t)NLAYERS * (2048*512 + 64*1024 + 512*1024) * 4ull;
  int nb = 16;
  while (nb > 1 &&
         ((size_t)nb * L_SEQ * per_m_bytes + (size_t)nb * cf_per_b + wpack_bytes + 16 * DM * 4) > ws_size)
    nb >>= 1;
  int Mc = nb * L_SEQ;

  char* p = (char*)d_ws;
  float* h      = (float*)p; p += (size_t)Mc * DM   * 4;
  float* xz     = (float*)p; p += (size_t)Mc * 2048 * 4;
  float* u      = (float*)p; p += (size_t)Mc * DI   * 4;
  float* dblb   = (float*)p; p += (size_t)Mc * 64   * 4;
  float* dtv    = (float*)p; p += (size_t)Mc * DI   * 4;
  char*  hP     = p;         p += (size_t)Mc * DM   * 4;
  char*  uP     = p;         p += (size_t)Mc * DI   * 4;
  char*  yP     = p;         p += (size_t)Mc * DI   * 4;
  float* cfF    = (float*)p; p += (size_t)nb * NC * DI * DSTATE * 4;
  float* cfP    = (float*)p; p += (size_t)nb * NC * DI * DSTATE * 4;
  char*  ipwP   = p;         p += (size_t)NLAYERS * 2048 * 512 * 4;
  char*  xpwP   = p;         p += (size_t)NLAYERS * 64 * 1024 * 4;
  char*  opwP   = p;         p += (size_t)NLAYERS * 512 * 1024 * 4;
  float* pooled = (float*)p;

  hipMemsetAsync(pooled, 0, 16 * DM * 4, stream);

  // pack all weights once (outside batch-chunk loop)
  for (int layer = 0; layer < NLAYERS; ++layer) {
    pack_hl<<<(2048*512/8 + 255)/256, 256, 0, stream>>>(
        ipw + (size_t)layer*2048*DM, ipwP + (size_t)layer*2048*512*4, 2048*512/8);
    pack_hl<<<(64*1024/8 + 255)/256, 256, 0, stream>>>(
        xpw + (size_t)layer*64*DI, xpwP + (size_t)layer*64*1024*4, 64*1024/8);
    pack_hl<<<(512*1024/8 + 255)/256, 256, 0, stream>>>(
        opw + (size_t)layer*DM*DI, opwP + (size_t)layer*512*1024*4, 512*1024/8);
  }

  for (int b0 = 0; b0 < 16; b0 += nb) {
    embed_kernel<<<Mc / 4, 256, 0, stream>>>(x, in_w, in_b, h, hP, b0, Mc);
    for (int layer = 0; layer < NLAYERS; ++layer) {
      const float* cw_l   = cw   + (size_t)layer * DI * 4;
      const float* cb_l   = cb   + (size_t)layer * DI;
      const float* dtw_l  = dtw  + (size_t)layer * DI * 32;
      const float* dtb_l  = dtb  + (size_t)layer * DI;
      const float* Alog_l = Alog + (size_t)layer * DI * DSTATE;
      const float* Dp_l   = Dp   + (size_t)layer * DI;

      gemm_pk3<<<dim3(2048 / BN, Mc / BM), 256, 0, stream>>>(
          hP, ipwP + (size_t)layer*2048*512*4, xz, 512, 2048);
      conv_silu_kernel<<<Mc / 2, 256, 0, stream>>>(xz, cw_l, cb_l, u, uP, Mc);
      gemm_pk3<<<dim3(1, Mc / BM), 256, 0, stream>>>(
          uP, xpwP + (size_t)layer*64*1024*4, dblb, 1024, 64);
      dt_tile<<<dim3(Mc / 64, 16), 256, 0, stream>>>(dblb, dtw_l, dtb_l, dtv);
      scan_pass1<<<dim3(16, NC - 1, nb), 256, 0, stream>>>(dtv, u, dblb, Alog_l, cfF, cfP);
      chunk_prefix<<<(nb * DI + 255) / 256, 256, 0, stream>>>(cfF, cfP, nb);
      scan_pass3<<<dim3(16, NC, nb), 256, 0, stream>>>(dtv, u, xz, dblb, Alog_l, Dp_l, cfF, yP);
      gemm_pk3<<<dim3(DM / BN, Mc / BM), 256, 0, stream>>>(
          yP, opwP + (size_t)layer*512*1024*4, h, 1024, DM);
      if (layer < NLAYERS - 1)
        pack_hl<<<(Mc * DM / 8 + 255)/256, 256, 0, stream>>>(h, hP, Mc * DM / 8);
    }
    pool_kernel<<<nb * 32, 512, 0, stream>>>(h, pooled, b0);
  }
  head_kernel<<<16, 512, 0, stream>>>(pooled, nw, nbv, clw, clb, out);
}

// Round 4
// 11697.697 us; speedup vs baseline: 1.4606x; 1.4606x over previous
//
#include <hip/hip_runtime.h>
#include <hip/hip_bf16.h>
#include <math.h>

#define L_SEQ 4096
#define DM 512
#define DI 1024
#define DSTATE 16
#define NLAYERS 4
#define NC 64         // scan chunks (parallelism source at small batch)
#define LC 64         // chunk length = L_SEQ / NC
#define TT 16         // timestep tile

typedef __bf16 v8bf __attribute__((ext_vector_type(8)));
typedef __bf16 v4bf __attribute__((ext_vector_type(4)));
typedef float  v4f  __attribute__((ext_vector_type(4)));

static __device__ __forceinline__ v4f mfma16(v8bf a, v8bf b, v4f c) {
  return __builtin_amdgcn_mfma_f32_16x16x32_bf16(a, b, c, 0, 0, 0);
}

// async global->LDS DMA, 16B/lane (LDS dest wave-uniform; HW adds lane*16)
static __device__ __forceinline__ void lds_dma16(const void* g, void* l) {
  __builtin_amdgcn_global_load_lds(
      (const __attribute__((address_space(1))) void*)g,
      (__attribute__((address_space(3))) void*)l, 16, 0, 0);
}

// ---------------------------------------------------------------------------
// Packed hi/lo bf16 ("HL"): per row, kgroup g (8 elems) = 32B: [hi x8][lo x8].
// Row stride K*4 bytes; element d: hi at (d>>3)*32+(d&7)*2, lo at +16.
// ---------------------------------------------------------------------------
__global__ void pack_hl(const float* __restrict__ src, char* __restrict__ dst, int nunits) {
  int i = blockIdx.x * 256 + threadIdx.x;
  if (i >= nunits) return;
  const float4* s = reinterpret_cast<const float4*>(src) + (size_t)i * 2;
  float4 v0 = s[0], v1 = s[1];
  v8bf hi, lo;
  float f[8] = {v0.x, v0.y, v0.z, v0.w, v1.x, v1.y, v1.z, v1.w};
#pragma unroll
  for (int j = 0; j < 8; ++j) {
    hi[j] = (__bf16)f[j];
    lo[j] = (__bf16)(f[j] - (float)hi[j]);
  }
  *reinterpret_cast<v8bf*>(dst + (size_t)i * 32)      = hi;
  *reinterpret_cast<v8bf*>(dst + (size_t)i * 32 + 16) = lo;
}

// ---------------------------------------------------------------------------
// Embed -> packed h only. Thread = one kgroup (8 d's).
// ---------------------------------------------------------------------------
__global__ void embed_kernel(const float* __restrict__ x, const float* __restrict__ in_w,
                             const float* __restrict__ in_b, char* __restrict__ h_pack,
                             int b0, int Mc) {
  int idx = blockIdx.x * 256 + threadIdx.x;   // Mc*64 kgroups
  int g = idx & 63;
  int m = idx >> 6;
  if (m >= Mc) return;
  int d0 = g * 8;
  int bg = b0 + (m >> 12);
  int l  = m & (L_SEQ - 1);
  const float* xp = x + ((size_t)bg * 3) * L_SEQ + l;
  float x0 = xp[0], x1 = xp[L_SEQ], x2 = xp[2 * L_SEQ];
  v8bf hi, lo;
#pragma unroll
  for (int j = 0; j < 8; ++j) {
    int d = d0 + j;
    float f = in_b[d] + x0 * in_w[d*3+0] + x1 * in_w[d*3+1] + x2 * in_w[d*3+2];
    hi[j] = (__bf16)f;
    lo[j] = (__bf16)(f - (float)hi[j]);
  }
  char* pp = h_pack + (size_t)m * (DM * 4) + g * 32;
  *reinterpret_cast<v8bf*>(pp)      = hi;
  *reinterpret_cast<v8bf*>(pp + 16) = lo;
}

// ---------------------------------------------------------------------------
// Split-bf16 3-pass MFMA GEMM on packed HL. C[M][N] = A[M][K]*B[N][K]^T.
// BM=128 BN=64 BK=64, 256 thr. global_load_lds w=16, XOR-swizzled LDS.
// grid: (x = M-blocks, y = N-blocks) so consecutive blocks share B panel.
// ---------------------------------------------------------------------------
#define BM 128
#define BN 64
#define BK 64

__global__ __launch_bounds__(256) void gemm_pk3(
    const char* __restrict__ Ap, const char* __restrict__ Bp, float* __restrict__ C,
    int K, int ldc) {
  __shared__ __align__(16) char lds[49152];   // A 32KB, B 16KB
  int tid = threadIdx.x;
  int w = tid >> 6, lane = tid & 63;
  int m0 = blockIdx.x * BM, n0 = blockIdx.y * BN;
  int Ku = K >> 2;
  int lrow = lane & 15, lq = lane >> 4;
  int sw = lrow & 7;

  const char* aBase[8];
  const char* bBase[4];
#pragma unroll
  for (int i = 0; i < 8; ++i) {
    int row = w * 32 + i * 4 + (lane >> 4);
    int uu  = (lane & 15) ^ (row & 7);
    aBase[i] = Ap + ((size_t)(m0 + row) * Ku + uu) * 16;
  }
#pragma unroll
  for (int i = 0; i < 4; ++i) {
    int row = w * 16 + i * 4 + (lane >> 4);
    int uu  = (lane & 15) ^ (row & 7);
    bBase[i] = Bp + ((size_t)(n0 + row) * Ku + uu) * 16;
  }
  char* aLdsW = lds + w * 8192;
  char* bLdsW = lds + 32768 + w * 4096;

  v4f acc[2][4];
#pragma unroll
  for (int i = 0; i < 2; ++i)
#pragma unroll
    for (int j = 0; j < 4; ++j)
#pragma unroll
      for (int e = 0; e < 4; ++e) acc[i][j][e] = 0.0f;

  size_t koff = 0;
  for (int k0 = 0; k0 < K; k0 += BK, koff += 256) {
    __syncthreads();
#pragma unroll
    for (int i = 0; i < 8; ++i) lds_dma16(aBase[i] + koff, aLdsW + i * 1024);
#pragma unroll
    for (int i = 0; i < 4; ++i) lds_dma16(bBase[i] + koff, bLdsW + i * 1024);
    __syncthreads();

#pragma unroll
    for (int kk = 0; kk < 2; ++kk) {
      int u2 = (kk * 4 + lq) * 2;
      int o_hi = ((u2    ) ^ sw) << 4;
      int o_lo = ((u2 + 1) ^ sw) << 4;
      v8bf aF[2][2], bF[4][2];
#pragma unroll
      for (int mt = 0; mt < 2; ++mt) {
        const char* pa = lds + (w * 32 + mt * 16 + lrow) * 256;
        aF[mt][0] = *reinterpret_cast<const v8bf*>(pa + o_hi);
        aF[mt][1] = *reinterpret_cast<const v8bf*>(pa + o_lo);
      }
#pragma unroll
      for (int nt = 0; nt < 4; ++nt) {
        const char* pb = lds + 32768 + (nt * 16 + lrow) * 256;
        bF[nt][0] = *reinterpret_cast<const v8bf*>(pb + o_hi);
        bF[nt][1] = *reinterpret_cast<const v8bf*>(pb + o_lo);
      }
#pragma unroll
      for (int mt = 0; mt < 2; ++mt)
#pragma unroll
        for (int nt = 0; nt < 4; ++nt) {
          acc[mt][nt] = mfma16(aF[mt][0], bF[nt][0], acc[mt][nt]);
          acc[mt][nt] = mfma16(aF[mt][0], bF[nt][1], acc[mt][nt]);
          acc[mt][nt] = mfma16(aF[mt][1], bF[nt][0], acc[mt][nt]);
        }
    }
  }

#pragma unroll
  for (int mt = 0; mt < 2; ++mt)
#pragma unroll
    for (int nt = 0; nt < 4; ++nt) {
      int rbase = m0 + w * 32 + mt * 16 + lq * 4;
      int cidx  = n0 + nt * 16 + lrow;
#pragma unroll
      for (int r = 0; r < 4; ++r)
        C[(size_t)(rbase + r) * ldc + cidx] = acc[mt][nt][r];
    }
}

// ---------------------------------------------------------------------------
// Depthwise causal conv(k=4) + bias + SiLU -> packed u only.
// ---------------------------------------------------------------------------
__global__ void conv_silu_kernel(const float* __restrict__ xz, const float* __restrict__ cw,
                                 const float* __restrict__ cb,
                                 char* __restrict__ u_pack, int Mc) {
  int idx = blockIdx.x * 256 + threadIdx.x;   // Mc*128 kgroups
  int g = idx & 127;
  int m = idx >> 7;
  if (m >= Mc) return;
  int d0 = g * 8;
  int t = m & (L_SEQ - 1);
  float r[8];
  {
    const float4* cbp = reinterpret_cast<const float4*>(cb + d0);
    float4 c0 = cbp[0], c1 = cbp[1];
    r[0]=c0.x; r[1]=c0.y; r[2]=c0.z; r[3]=c0.w; r[4]=c1.x; r[5]=c1.y; r[6]=c1.z; r[7]=c1.w;
  }
#pragma unroll
  for (int k = 0; k < 4; ++k) {
    if (t + k >= 3) {
      const float4* src = reinterpret_cast<const float4*>(xz + (size_t)(m + k - 3) * 2048 + d0);
      float4 v0 = src[0], v1 = src[1];
      float vv[8] = {v0.x, v0.y, v0.z, v0.w, v1.x, v1.y, v1.z, v1.w};
#pragma unroll
      for (int j = 0; j < 8; ++j) r[j] += vv[j] * cw[(d0 + j) * 4 + k];
    }
  }
  v8bf hi, lo;
#pragma unroll
  for (int j = 0; j < 8; ++j) {
    r[j] = r[j] / (1.0f + expf(-r[j]));
    hi[j] = (__bf16)r[j];
    lo[j] = (__bf16)(r[j] - (float)hi[j]);
  }
  char* pp = u_pack + (size_t)m * (DI * 4) + g * 32;
  *reinterpret_cast<v8bf*>(pp)      = hi;
  *reinterpret_cast<v8bf*>(pp + 16) = lo;
}

// ---------------------------------------------------------------------------
// dt tile: dt[m][d] = softplus(dbl[m][0:32].dtw[d][:] + dtb[d])
// ---------------------------------------------------------------------------
__global__ __launch_bounds__(256) void dt_tile(const float* __restrict__ dbl,
                                               const float* __restrict__ dtw,
                                               const float* __restrict__ dtb,
                                               float* __restrict__ dt) {
  __shared__ float s_a[64][33];
  __shared__ float s_w[64][33];
  int tid = threadIdx.x;
  int m0 = blockIdx.x * 64, d0 = blockIdx.y * 64;
#pragma unroll
  for (int i = 0; i < 8; ++i) {
    int idx = tid + i * 256;
    int r = idx >> 5, cc = idx & 31;
    s_a[r][cc] = dbl[(size_t)(m0 + r) * 64 + cc];
    s_w[r][cc] = dtw[(size_t)(d0 + r) * 32 + cc];
  }
  __syncthreads();
  int tm = tid >> 4, td = tid & 15;
  float acc[4][4];
#pragma unroll
  for (int i = 0; i < 4; ++i)
#pragma unroll
    for (int j = 0; j < 4; ++j) acc[i][j] = dtb[d0 + td + 16 * j];
#pragma unroll
  for (int k = 0; k < 32; ++k) {
    float a_[4], w_[4];
#pragma unroll
    for (int i = 0; i < 4; ++i) a_[i] = s_a[tm * 4 + i][k];
#pragma unroll
    for (int j = 0; j < 4; ++j) w_[j] = s_w[td + 16 * j][k];
#pragma unroll
    for (int i = 0; i < 4; ++i)
#pragma unroll
      for (int j = 0; j < 4; ++j) acc[i][j] += a_[i] * w_[j];
  }
#pragma unroll
  for (int i = 0; i < 4; ++i)
#pragma unroll
    for (int j = 0; j < 4; ++j) {
      float v = acc[i][j];
      float sp = (v > 15.0f) ? v : log1pf(expf(v));
      dt[(size_t)(m0 + tm * 4 + i) * DI + d0 + td + 16 * j] = sp;
    }
}

// ---------------------------------------------------------------------------
// Scan pass 1: per chunk from h=0: final state + decay product.
// grid (16 dgroups, NC-1 chunks, nb). u read from packed HL.
// ---------------------------------------------------------------------------
__global__ __launch_bounds__(256) void scan_pass1(
    const float* __restrict__ dt, const char* __restrict__ uP,
    const float* __restrict__ dbl, const float* __restrict__ Alog,
    float* __restrict__ cfF, float* __restrict__ cfP) {
  __shared__ __align__(16) float s_dt[TT][64];
  __shared__ __align__(16) char  s_up[TT][256];
  __shared__ __align__(16) float s_b [TT][16];
  int tid = threadIdx.x;
  int d0 = blockIdx.x * 64;
  int c  = blockIdx.y;
  int bi = blockIdx.z;
  int dl = tid >> 2;
  int sg = (tid & 3) * 4;
  int d  = d0 + dl;
  float a2[4], h[4] = {0.f,0.f,0.f,0.f}, p[4] = {1.f,1.f,1.f,1.f};
#pragma unroll
  for (int j = 0; j < 4; ++j)
    a2[j] = -expf(Alog[(size_t)d * DSTATE + sg + j]) * 1.44269504088896340736f;
  size_t mbase = (size_t)bi * L_SEQ + (size_t)c * LC;
  int tr = tid >> 4, c4 = (tid & 15) * 4;
  int upo = (dl >> 3) * 32 + (dl & 7) * 2;

  for (int t0 = 0; t0 < LC; t0 += TT) {
    size_t m = mbase + t0 + tr;
    *reinterpret_cast<float4*>(&s_dt[tr][c4]) = *reinterpret_cast<const float4*>(dt + m*DI + d0 + c4);
    *reinterpret_cast<float4*>(&s_up[tr][(tid & 15) * 16]) =
        *reinterpret_cast<const float4*>(uP + m * (DI*4) + d0 * 4 + (tid & 15) * 16);
    if (tid < 64) {
      int tr3 = tid >> 2, cB = (tid & 3) * 4;
      *reinterpret_cast<float4*>(&s_b[tr3][cB]) =
          *reinterpret_cast<const float4*>(dbl + (mbase + t0 + tr3)*64 + 32 + cB);
    }
    __syncthreads();
#pragma unroll
    for (int t = 0; t < TT; ++t) {
      float dtv = s_dt[t][dl];
      float uv = (float)*reinterpret_cast<const __bf16*>(&s_up[t][upo])
               + (float)*reinterpret_cast<const __bf16*>(&s_up[t][upo + 16]);
      float cu  = dtv * uv;
      float4 Bv = *reinterpret_cast<const float4*>(&s_b[t][sg]);
      float dA;
      dA = exp2f(dtv * a2[0]); h[0] = dA*h[0] + cu*Bv.x; p[0] *= dA;
      dA = exp2f(dtv * a2[1]); h[1] = dA*h[1] + cu*Bv.y; p[1] *= dA;
      dA = exp2f(dtv * a2[2]); h[2] = dA*h[2] + cu*Bv.z; p[2] *= dA;
      dA = exp2f(dtv * a2[3]); h[3] = dA*h[3] + cu*Bv.w; p[3] *= dA;
    }
    __syncthreads();
  }
  size_t cbase = (((size_t)bi * NC + c) * DI + d) * DSTATE + sg;
  *reinterpret_cast<float4*>(cfF + cbase) = make_float4(h[0],h[1],h[2],h[3]);
  *reinterpret_cast<float4*>(cfP + cbase) = make_float4(p[0],p[1],p[2],p[3]);
}

// ---------------------------------------------------------------------------
// Scan pass 2: serial prefix over NC chunks (final -> entry), in place.
// One thread per (b,d,state-quad); 8-wide prefetch pipelining.
// ---------------------------------------------------------------------------
__global__ __launch_bounds__(256) void chunk_prefix(float* __restrict__ cfF,
                                                    const float* __restrict__ cfP,
                                                    int nb) {
  int gid = blockIdx.x * 256 + threadIdx.x;
  if (gid >= nb * DI * 4) return;
  int bi = gid >> 12;
  int d  = (gid >> 2) & (DI - 1);
  int q  = gid & 3;
  size_t base = (((size_t)bi * NC) * DI + d) * DSTATE + q * 4;
  const size_t cs = (size_t)DI * DSTATE;
  float4 carry = make_float4(0.f, 0.f, 0.f, 0.f);
  for (int c0 = 0; c0 < NC; c0 += 8) {
    float4 f[8], p[8];
#pragma unroll
    for (int i = 0; i < 8; ++i) {
      int c = c0 + i;
      if (c < NC - 1) {
        f[i] = *reinterpret_cast<const float4*>(cfF + base + (size_t)c * cs);
        p[i] = *reinterpret_cast<const float4*>(cfP + base + (size_t)c * cs);
      }
    }
#pragma unroll
    for (int i = 0; i < 8; ++i) {
      int c = c0 + i;
      *reinterpret_cast<float4*>(cfF + base + (size_t)c * cs) = carry;
      if (c < NC - 1) {
        carry.x = p[i].x * carry.x + f[i].x;
        carry.y = p[i].y * carry.y + f[i].y;
        carry.z = p[i].z * carry.z + f[i].z;
        carry.w = p[i].w * carry.w + f[i].w;
      }
    }
  }
}

// ---------------------------------------------------------------------------
// Scan pass 3: scan from entry state + gate; writes packed y IN PLACE into uP
// (each (m,d) owned by exactly one block; pass1 finished reading uP already).
// ---------------------------------------------------------------------------
__global__ __launch_bounds__(256) void scan_pass3(
    const float* __restrict__ dt, char* __restrict__ uP,
    const float* __restrict__ xz, const float* __restrict__ dbl,
    const float* __restrict__ Alog, const float* __restrict__ Dp,
    const float* __restrict__ cfF) {
  __shared__ __align__(16) float s_dt[TT][64];
  __shared__ __align__(16) char  s_up[TT][256];
  __shared__ __align__(16) float s_z [TT][64];
  __shared__ __align__(16) float s_bc[TT][32];
  __shared__ __align__(16) float s_y [TT][64];
  int tid = threadIdx.x;
  int d0 = blockIdx.x * 64;
  int c  = blockIdx.y;
  int bi = blockIdx.z;
  int dl = tid >> 2;
  int sg = (tid & 3) * 4;
  int d  = d0 + dl;
  float a2[4], hst[4];
  size_t cbase = (((size_t)bi * NC + c) * DI + d) * DSTATE + sg;
  float4 ent = *reinterpret_cast<const float4*>(cfF + cbase);
  hst[0]=ent.x; hst[1]=ent.y; hst[2]=ent.z; hst[3]=ent.w;
#pragma unroll
  for (int j = 0; j < 4; ++j)
    a2[j] = -expf(Alog[(size_t)d * DSTATE + sg + j]) * 1.44269504088896340736f;
  float dp = Dp[d];
  size_t mbase = (size_t)bi * L_SEQ + (size_t)c * LC;

  int tr = tid >> 4, c4 = (tid & 15) * 4;
  int tr2 = tid >> 3, c2 = (tid & 7) * 4;
  int upo = (dl >> 3) * 32 + (dl & 7) * 2;

  for (int t0 = 0; t0 < LC; t0 += TT) {
    size_t m = mbase + t0 + tr;
    *reinterpret_cast<float4*>(&s_dt[tr][c4]) = *reinterpret_cast<const float4*>(dt + m*DI + d0 + c4);
    *reinterpret_cast<float4*>(&s_up[tr][(tid & 15) * 16]) =
        *reinterpret_cast<const float4*>(uP + m * (DI*4) + d0 * 4 + (tid & 15) * 16);
    *reinterpret_cast<float4*>(&s_z [tr][c4]) = *reinterpret_cast<const float4*>(xz + m*2048 + DI + d0 + c4);
    if (tid < 128) {
      size_t m2 = mbase + t0 + tr2;
      *reinterpret_cast<float4*>(&s_bc[tr2][c2]) = *reinterpret_cast<const float4*>(dbl + m2*64 + 32 + c2);
    }
    __syncthreads();
#pragma unroll
    for (int t = 0; t < TT; ++t) {
      float dtv = s_dt[t][dl];
      float uv = (float)*reinterpret_cast<const __bf16*>(&s_up[t][upo])
               + (float)*reinterpret_cast<const __bf16*>(&s_up[t][upo + 16]);
      float cu  = dtv * uv;
      float4 Bv = *reinterpret_cast<const float4*>(&s_bc[t][sg]);
      float4 Cv = *reinterpret_cast<const float4*>(&s_bc[t][16 + sg]);
      float yp = 0.0f;
      {
        float dA;
        dA = exp2f(dtv * a2[0]); hst[0] = dA*hst[0] + cu*Bv.x; yp += hst[0]*Cv.x;
        dA = exp2f(dtv * a2[1]); hst[1] = dA*hst[1] + cu*Bv.y; yp += hst[1]*Cv.y;
        dA = exp2f(dtv * a2[2]); hst[2] = dA*hst[2] + cu*Bv.z; yp += hst[2]*Cv.z;
        dA = exp2f(dtv * a2[3]); hst[3] = dA*hst[3] + cu*Bv.w; yp += hst[3]*Cv.w;
      }
      yp += __shfl_xor(yp, 1);
      yp += __shfl_xor(yp, 2);
      if ((tid & 3) == 0) {
        float zv = s_z[t][dl];
        s_y[t][dl] = (yp + uv * dp) * (zv / (1.0f + expf(-zv)));
      }
    }
    __syncthreads();
    {
      float4 v = *reinterpret_cast<float4*>(&s_y[tr][c4]);
      int dgl = d0 + c4;
      v4bf hi, lo;
      float f[4] = {v.x, v.y, v.z, v.w};
#pragma unroll
      for (int j = 0; j < 4; ++j) {
        hi[j] = (__bf16)f[j];
        lo[j] = (__bf16)(f[j] - (float)hi[j]);
      }
      char* pp = uP + m * (DI*4) + (dgl >> 3) * 32 + ((dgl & 7) * 2);
      *reinterpret_cast<v4bf*>(pp)      = hi;
      *reinterpret_cast<v4bf*>(pp + 16) = lo;
    }
    __syncthreads();
  }
}

// ---------------------------------------------------------------------------
// Pool (reads fp32 h written by final out_proj)
// ---------------------------------------------------------------------------
__global__ __launch_bounds__(512) void pool_kernel(const float* __restrict__ h,
                                                   float* __restrict__ pooled,
                                                   int b0) {
  int b = blockIdx.x >> 5;
  int chunk = blockIdx.x & 31;
  int d = threadIdx.x;
  float s = 0.0f;
  size_t base = (size_t)b * L_SEQ + chunk * 128;
  for (int l = 0; l < 128; ++l) s += h[(base + l) * DM + d];
  atomicAdd(pooled + (size_t)(b0 + b) * DM + d, s * (1.0f / 4096.0f));
}

// ---------------------------------------------------------------------------
// Head: LayerNorm + classifier
// ---------------------------------------------------------------------------
__global__ __launch_bounds__(512) void head_kernel(const float* __restrict__ pooled,
                                                   const float* __restrict__ nw,
                                                   const float* __restrict__ nbv,
                                                   const float* __restrict__ clw,
                                                   const float* __restrict__ clb,
                                                   float* __restrict__ out) {
  __shared__ float rs[8], rq[8];
  __shared__ float ln[512];
  int b = blockIdx.x, tid = threadIdx.x;
  int wid = tid >> 6, lane = tid & 63;
  float v = pooled[(size_t)b * DM + tid];
  float s = v, q = v * v;
#pragma unroll
  for (int off = 1; off < 64; off <<= 1) { s += __shfl_xor(s, off); q += __shfl_xor(q, off); }
  if (lane == 0) { rs[wid] = s; rq[wid] = q; }
  __syncthreads();
  if (tid == 0) {
    float S = 0, Q = 0;
    for (int i = 0; i < 8; ++i) { S += rs[i]; Q += rq[i]; }
    rs[0] = S; rq[0] = Q;
  }
  __syncthreads();
  float mu  = rs[0] / 512.0f;
  float var = rq[0] / 512.0f - mu * mu;
  ln[tid] = (v - mu) * rsqrtf(var + 1e-5f) * nw[tid] + nbv[tid];
  __syncthreads();
  if (tid < 320) {
    int c = tid >> 5, l2 = tid & 31;
    float p = 0.0f;
    for (int dd = l2; dd < 512; dd += 32) p += ln[dd] * clw[c * 512 + dd];
#pragma unroll
    for (int off = 1; off < 32; off <<= 1) p += __shfl_xor(p, off);
    if (l2 == 0) out[(size_t)b * 10 + c] = p + clb[c];
  }
}

// ---------------------------------------------------------------------------
extern "C" void kernel_launch(void* const* d_in, const int* in_sizes, int n_in,
                              void* d_out, int out_size, void* d_ws, size_t ws_size,
                              hipStream_t stream) {
  (void)in_sizes; (void)n_in; (void)out_size;
  const float* x    = (const float*)d_in[0];
  const float* in_w = (const float*)d_in[1];
  const float* in_b = (const float*)d_in[2];
  const float* ipw  = (const float*)d_in[3];
  const float* cw   = (const float*)d_in[4];
  const float* cb   = (const float*)d_in[5];
  const float* xpw  = (const float*)d_in[6];
  const float* dtw  = (const float*)d_in[7];
  const float* dtb  = (const float*)d_in[8];
  const float* Alog = (const float*)d_in[9];
  const float* Dp   = (const float*)d_in[10];
  const float* opw  = (const float*)d_in[11];
  const float* nw   = (const float*)d_in[12];
  const float* nbv  = (const float*)d_in[13];
  const float* clw  = (const float*)d_in[14];
  const float* clb  = (const float*)d_in[15];
  float* out = (float*)d_out;

  // per-token floats: h 512 + xz 2048 + uP 1024 + dbl 64 + dt 1024 + hP 512 = 5184
  const size_t per_m_bytes = 5184ull * 4ull;
  const size_t wpack_bytes = (size_t)NLAYERS * (2048*512 + 64*1024 + 512*1024) * 4ull;
  int nb = 16;
  while (nb > 1 &&
         ((size_t)nb * L_SEQ * per_m_bytes
          + (size_t)nb * 2ull * NC * DI * DSTATE * 4ull
          + wpack_bytes + 16 * DM * 4 + 1024) > ws_size)
    nb >>= 1;
  int Mc = nb * L_SEQ;

  char* p = (char*)d_ws;
  float* h      = (float*)p; p += (size_t)Mc * DM   * 4;
  float* xz     = (float*)p; p += (size_t)Mc * 2048 * 4;
  char*  uPb    = p;         p += (size_t)Mc * DI   * 4;
  float* dblb   = (float*)p; p += (size_t)Mc * 64   * 4;
  float* dtv    = (float*)p; p += (size_t)Mc * DI   * 4;
  char*  hP     = p;         p += (size_t)Mc * DM   * 4;
  float* cfF    = (float*)p; p += (size_t)nb * NC * DI * DSTATE * 4;
  float* cfP    = (float*)p; p += (size_t)nb * NC * DI * DSTATE * 4;
  char*  ipwP   = p;         p += (size_t)NLAYERS * 2048 * 512 * 4;
  char*  xpwP   = p;         p += (size_t)NLAYERS * 64 * 1024 * 4;
  char*  opwP   = p;         p += (size_t)NLAYERS * 512 * 1024 * 4;
  float* pooled = (float*)p;

  hipMemsetAsync(pooled, 0, 16 * DM * 4, stream);

  for (int layer = 0; layer < NLAYERS; ++layer) {
    pack_hl<<<(2048*512/8 + 255)/256, 256, 0, stream>>>(
        ipw + (size_t)layer*2048*DM, ipwP + (size_t)layer*2048*512*4, 2048*512/8);
    pack_hl<<<(64*1024/8 + 255)/256, 256, 0, stream>>>(
        xpw + (size_t)layer*64*DI, xpwP + (size_t)layer*64*1024*4, 64*1024/8);
    pack_hl<<<(512*1024/8 + 255)/256, 256, 0, stream>>>(
        opw + (size_t)layer*DM*DI, opwP + (size_t)layer*512*1024*4, 512*1024/8);
  }

  for (int b0 = 0; b0 < 16; b0 += nb) {
    embed_kernel<<<Mc / 4, 256, 0, stream>>>(x, in_w, in_b, hP, b0, Mc);
    for (int layer = 0; layer < NLAYERS; ++layer) {
      const float* cw_l   = cw   + (size_t)layer * DI * 4;
      const float* cb_l   = cb   + (size_t)layer * DI;
      const float* dtw_l  = dtw  + (size_t)layer * DI * 32;
      const float* dtb_l  = dtb  + (size_t)layer * DI;
      const float* Alog_l = Alog + (size_t)layer * DI * DSTATE;
      const float* Dp_l   = Dp   + (size_t)layer * DI;

      gemm_pk3<<<dim3(Mc / BM, 2048 / BN), 256, 0, stream>>>(
          hP, ipwP + (size_t)layer*2048*512*4, xz, 512, 2048);
      conv_silu_kernel<<<Mc / 2, 256, 0, stream>>>(xz, cw_l, cb_l, uPb, Mc);
      gemm_pk3<<<dim3(Mc / BM, 1), 256, 0, stream>>>(
          uPb, xpwP + (size_t)layer*64*1024*4, dblb, 1024, 64);
      dt_tile<<<dim3(Mc / 64, 16), 256, 0, stream>>>(dblb, dtw_l, dtb_l, dtv);
      scan_pass1<<<dim3(16, NC - 1, nb), 256, 0, stream>>>(dtv, uPb, dblb, Alog_l, cfF, cfP);
      chunk_prefix<<<(nb * DI * 4 + 255) / 256, 256, 0, stream>>>(cfF, cfP, nb);
      scan_pass3<<<dim3(16, NC, nb), 256, 0, stream>>>(dtv, uPb, xz, dblb, Alog_l, Dp_l, cfF);
      gemm_pk3<<<dim3(Mc / BM, DM / BN), 256, 0, stream>>>(
          uPb, opwP + (size_t)layer*512*1024*4, h, 1024, DM);
      if (layer < NLAYERS - 1)
        pack_hl<<<(Mc * DM / 8 + 255)/256, 256, 0, stream>>>(h, hP, Mc * DM / 8);
    }
    pool_kernel<<<nb * 32, 512, 0, stream>>>(h, pooled, b0);
  }
  head_kernel<<<16, 512, 0, stream>>>(pooled, nw, nbv, clw, clb, out);
}

// Round 5
// 11196.409 us; speedup vs baseline: 1.5260x; 1.0448x over previous
//
#include <hip/hip_runtime.h>
#include <hip/hip_bf16.h>
#include <math.h>

#define L_SEQ 4096
#define DM 512
#define DI 1024
#define DSTATE 16
#define NLAYERS 4
#define NC 64         // scan chunks
#define LC 64         // chunk length = L_SEQ / NC
#define TT 16         // timestep tile

typedef __bf16 v8bf __attribute__((ext_vector_type(8)));
typedef __bf16 v4bf __attribute__((ext_vector_type(4)));
typedef float  v4f  __attribute__((ext_vector_type(4)));

static __device__ __forceinline__ v4f mfma16(v8bf a, v8bf b, v4f c) {
  return __builtin_amdgcn_mfma_f32_16x16x32_bf16(a, b, c, 0, 0, 0);
}

// async global->LDS DMA, 16B/lane (LDS dest wave-uniform; HW adds lane*16)
static __device__ __forceinline__ void lds_dma16(const void* g, void* l) {
  __builtin_amdgcn_global_load_lds(
      (const __attribute__((address_space(1))) void*)g,
      (__attribute__((address_space(3))) void*)l, 16, 0, 0);
}

// ---------------------------------------------------------------------------
// Packed hi/lo bf16 ("HL"): per row, kgroup g (8 elems) = 32B: [hi x8][lo x8].
// Row stride K*4 bytes; element d: hi at (d>>3)*32+(d&7)*2, lo at +16.
// ---------------------------------------------------------------------------
__global__ void pack_hl(const float* __restrict__ src, char* __restrict__ dst, int nunits) {
  int i = blockIdx.x * 256 + threadIdx.x;
  if (i >= nunits) return;
  const float4* s = reinterpret_cast<const float4*>(src) + (size_t)i * 2;
  float4 v0 = s[0], v1 = s[1];
  v8bf hi, lo;
  float f[8] = {v0.x, v0.y, v0.z, v0.w, v1.x, v1.y, v1.z, v1.w};
#pragma unroll
  for (int j = 0; j < 8; ++j) {
    hi[j] = (__bf16)f[j];
    lo[j] = (__bf16)(f[j] - (float)hi[j]);
  }
  *reinterpret_cast<v8bf*>(dst + (size_t)i * 32)      = hi;
  *reinterpret_cast<v8bf*>(dst + (size_t)i * 32 + 16) = lo;
}

// ---------------------------------------------------------------------------
// Embed -> packed h only.
// ---------------------------------------------------------------------------
__global__ void embed_kernel(const float* __restrict__ x, const float* __restrict__ in_w,
                             const float* __restrict__ in_b, char* __restrict__ h_pack,
                             int b0, int Mc) {
  int idx = blockIdx.x * 256 + threadIdx.x;   // Mc*64 kgroups
  int g = idx & 63;
  int m = idx >> 6;
  if (m >= Mc) return;
  int d0 = g * 8;
  int bg = b0 + (m >> 12);
  int l  = m & (L_SEQ - 1);
  const float* xp = x + ((size_t)bg * 3) * L_SEQ + l;
  float x0 = xp[0], x1 = xp[L_SEQ], x2 = xp[2 * L_SEQ];
  v8bf hi, lo;
#pragma unroll
  for (int j = 0; j < 8; ++j) {
    int d = d0 + j;
    float f = in_b[d] + x0 * in_w[d*3+0] + x1 * in_w[d*3+1] + x2 * in_w[d*3+2];
    hi[j] = (__bf16)f;
    lo[j] = (__bf16)(f - (float)hi[j]);
  }
  char* pp = h_pack + (size_t)m * (DM * 4) + g * 32;
  *reinterpret_cast<v8bf*>(pp)      = hi;
  *reinterpret_cast<v8bf*>(pp + 16) = lo;
}

// ---------------------------------------------------------------------------
// Split-bf16 3-pass MFMA GEMM on packed HL. C[M][N] = A[M][K]*B[N][K]^T.
// BM=128 BN=64 BK=64. Kstride = full row K (addressing), k_len = this block's
// K-slice (split-K via blockIdx.z when gridDim.z>1). EPI: 0=store, 1=atomicAdd.
// ---------------------------------------------------------------------------
#define BM 128
#define BN 64
#define BK 64

template <int EPI>
__global__ __launch_bounds__(256) void gemm_pk3(
    const char* __restrict__ Ap, const char* __restrict__ Bp, float* __restrict__ C,
    int Kstride, int k_len, int ldc) {
  __shared__ __align__(16) char lds[49152];   // A 32KB, B 16KB
  int tid = threadIdx.x;
  int w = tid >> 6, lane = tid & 63;
  int m0 = blockIdx.x * BM, n0 = blockIdx.y * BN;
  int k0s = blockIdx.z * k_len;
  int Ku = Kstride >> 2;
  int lrow = lane & 15, lq = lane >> 4;
  int sw = lrow & 7;

  const char* aBase[8];
  const char* bBase[4];
#pragma unroll
  for (int i = 0; i < 8; ++i) {
    int row = w * 32 + i * 4 + (lane >> 4);
    int uu  = (lane & 15) ^ (row & 7);
    aBase[i] = Ap + ((size_t)(m0 + row) * Ku + uu + (k0s >> 2)) * 16;
  }
#pragma unroll
  for (int i = 0; i < 4; ++i) {
    int row = w * 16 + i * 4 + (lane >> 4);
    int uu  = (lane & 15) ^ (row & 7);
    bBase[i] = Bp + ((size_t)(n0 + row) * Ku + uu + (k0s >> 2)) * 16;
  }
  char* aLdsW = lds + w * 8192;
  char* bLdsW = lds + 32768 + w * 4096;

  v4f acc[2][4];
#pragma unroll
  for (int i = 0; i < 2; ++i)
#pragma unroll
    for (int j = 0; j < 4; ++j)
#pragma unroll
      for (int e = 0; e < 4; ++e) acc[i][j][e] = 0.0f;

  size_t koff = 0;
  for (int k0 = 0; k0 < k_len; k0 += BK, koff += 256) {
    __syncthreads();
#pragma unroll
    for (int i = 0; i < 8; ++i) lds_dma16(aBase[i] + koff, aLdsW + i * 1024);
#pragma unroll
    for (int i = 0; i < 4; ++i) lds_dma16(bBase[i] + koff, bLdsW + i * 1024);
    __syncthreads();

#pragma unroll
    for (int kk = 0; kk < 2; ++kk) {
      int u2 = (kk * 4 + lq) * 2;
      int o_hi = ((u2    ) ^ sw) << 4;
      int o_lo = ((u2 + 1) ^ sw) << 4;
      v8bf aF[2][2], bF[4][2];
#pragma unroll
      for (int mt = 0; mt < 2; ++mt) {
        const char* pa = lds + (w * 32 + mt * 16 + lrow) * 256;
        aF[mt][0] = *reinterpret_cast<const v8bf*>(pa + o_hi);
        aF[mt][1] = *reinterpret_cast<const v8bf*>(pa + o_lo);
      }
#pragma unroll
      for (int nt = 0; nt < 4; ++nt) {
        const char* pb = lds + 32768 + (nt * 16 + lrow) * 256;
        bF[nt][0] = *reinterpret_cast<const v8bf*>(pb + o_hi);
        bF[nt][1] = *reinterpret_cast<const v8bf*>(pb + o_lo);
      }
#pragma unroll
      for (int mt = 0; mt < 2; ++mt)
#pragma unroll
        for (int nt = 0; nt < 4; ++nt) {
          acc[mt][nt] = mfma16(aF[mt][0], bF[nt][0], acc[mt][nt]);
          acc[mt][nt] = mfma16(aF[mt][0], bF[nt][1], acc[mt][nt]);
          acc[mt][nt] = mfma16(aF[mt][1], bF[nt][0], acc[mt][nt]);
        }
    }
  }

#pragma unroll
  for (int mt = 0; mt < 2; ++mt)
#pragma unroll
    for (int nt = 0; nt < 4; ++nt) {
      int rbase = m0 + w * 32 + mt * 16 + lq * 4;
      int cidx  = n0 + nt * 16 + lrow;
#pragma unroll
      for (int r = 0; r < 4; ++r) {
        if (EPI == 0)
          C[(size_t)(rbase + r) * ldc + cidx] = acc[mt][nt][r];
        else
          atomicAdd(&C[(size_t)(rbase + r) * ldc + cidx], acc[mt][nt][r]);
      }
    }
}

// ---------------------------------------------------------------------------
// Depthwise causal conv(k=4) + bias + SiLU -> packed u only.
// ---------------------------------------------------------------------------
__global__ void conv_silu_kernel(const float* __restrict__ xz, const float* __restrict__ cw,
                                 const float* __restrict__ cb,
                                 char* __restrict__ u_pack, int Mc) {
  int idx = blockIdx.x * 256 + threadIdx.x;   // Mc*128 kgroups
  int g = idx & 127;
  int m = idx >> 7;
  if (m >= Mc) return;
  int d0 = g * 8;
  int t = m & (L_SEQ - 1);
  float r[8];
  {
    const float4* cbp = reinterpret_cast<const float4*>(cb + d0);
    float4 c0 = cbp[0], c1 = cbp[1];
    r[0]=c0.x; r[1]=c0.y; r[2]=c0.z; r[3]=c0.w; r[4]=c1.x; r[5]=c1.y; r[6]=c1.z; r[7]=c1.w;
  }
#pragma unroll
  for (int k = 0; k < 4; ++k) {
    if (t + k >= 3) {
      const float4* src = reinterpret_cast<const float4*>(xz + (size_t)(m + k - 3) * 2048 + d0);
      float4 v0 = src[0], v1 = src[1];
      float vv[8] = {v0.x, v0.y, v0.z, v0.w, v1.x, v1.y, v1.z, v1.w};
#pragma unroll
      for (int j = 0; j < 8; ++j) r[j] += vv[j] * cw[(d0 + j) * 4 + k];
    }
  }
  v8bf hi, lo;
#pragma unroll
  for (int j = 0; j < 8; ++j) {
    r[j] = r[j] / (1.0f + expf(-r[j]));
    hi[j] = (__bf16)r[j];
    lo[j] = (__bf16)(r[j] - (float)hi[j]);
  }
  char* pp = u_pack + (size_t)m * (DI * 4) + g * 32;
  *reinterpret_cast<v8bf*>(pp)      = hi;
  *reinterpret_cast<v8bf*>(pp + 16) = lo;
}

// ---------------------------------------------------------------------------
// dt tile: dt[m][d] = softplus(dbl[m][0:32].dtw[d][:] + dtb[d])
// dt is written into the (dead) xc half of xz: ld = 2048.
// ---------------------------------------------------------------------------
__global__ __launch_bounds__(256) void dt_tile(const float* __restrict__ dbl,
                                               const float* __restrict__ dtw,
                                               const float* __restrict__ dtb,
                                               float* __restrict__ dt, int ld) {
  __shared__ float s_a[64][33];
  __shared__ float s_w[64][33];
  int tid = threadIdx.x;
  int m0 = blockIdx.x * 64, d0 = blockIdx.y * 64;
#pragma unroll
  for (int i = 0; i < 8; ++i) {
    int idx = tid + i * 256;
    int r = idx >> 5, cc = idx & 31;
    s_a[r][cc] = dbl[(size_t)(m0 + r) * 64 + cc];
    s_w[r][cc] = dtw[(size_t)(d0 + r) * 32 + cc];
  }
  __syncthreads();
  int tm = tid >> 4, td = tid & 15;
  float acc[4][4];
#pragma unroll
  for (int i = 0; i < 4; ++i)
#pragma unroll
    for (int j = 0; j < 4; ++j) acc[i][j] = dtb[d0 + td + 16 * j];
#pragma unroll
  for (int k = 0; k < 32; ++k) {
    float a_[4], w_[4];
#pragma unroll
    for (int i = 0; i < 4; ++i) a_[i] = s_a[tm * 4 + i][k];
#pragma unroll
    for (int j = 0; j < 4; ++j) w_[j] = s_w[td + 16 * j][k];
#pragma unroll
    for (int i = 0; i < 4; ++i)
#pragma unroll
      for (int j = 0; j < 4; ++j) acc[i][j] += a_[i] * w_[j];
  }
#pragma unroll
  for (int i = 0; i < 4; ++i)
#pragma unroll
    for (int j = 0; j < 4; ++j) {
      float v = acc[i][j];
      float sp = (v > 15.0f) ? v : log1pf(expf(v));
      dt[(size_t)(m0 + tm * 4 + i) * ld + d0 + td + 16 * j] = sp;
    }
}

// ---------------------------------------------------------------------------
// Scan pass 1: per chunk from h=0: final state + decay product.
// dt read from xz cols [0,1024) (ld 2048); u from packed HL.
// ---------------------------------------------------------------------------
__global__ __launch_bounds__(256) void scan_pass1(
    const float* __restrict__ xzp, const char* __restrict__ uP,
    const float* __restrict__ dbl, const float* __restrict__ Alog,
    float* __restrict__ cfF, float* __restrict__ cfP) {
  __shared__ __align__(16) float s_dt[TT][64];
  __shared__ __align__(16) char  s_up[TT][256];
  __shared__ __align__(16) float s_b [TT][16];
  int tid = threadIdx.x;
  int d0 = blockIdx.x * 64;
  int c  = blockIdx.y;
  int bi = blockIdx.z;
  int dl = tid >> 2;
  int sg = (tid & 3) * 4;
  int d  = d0 + dl;
  float a2[4], h[4] = {0.f,0.f,0.f,0.f}, p[4] = {1.f,1.f,1.f,1.f};
#pragma unroll
  for (int j = 0; j < 4; ++j)
    a2[j] = -expf(Alog[(size_t)d * DSTATE + sg + j]) * 1.44269504088896340736f;
  size_t mbase = (size_t)bi * L_SEQ + (size_t)c * LC;
  int tr = tid >> 4, c4 = (tid & 15) * 4;
  int upo = (dl >> 3) * 32 + (dl & 7) * 2;

  for (int t0 = 0; t0 < LC; t0 += TT) {
    size_t m = mbase + t0 + tr;
    *reinterpret_cast<float4*>(&s_dt[tr][c4]) = *reinterpret_cast<const float4*>(xzp + m*2048 + d0 + c4);
    *reinterpret_cast<float4*>(&s_up[tr][(tid & 15) * 16]) =
        *reinterpret_cast<const float4*>(uP + m * (DI*4) + d0 * 4 + (tid & 15) * 16);
    if (tid < 64) {
      int tr3 = tid >> 2, cB = (tid & 3) * 4;
      *reinterpret_cast<float4*>(&s_b[tr3][cB]) =
          *reinterpret_cast<const float4*>(dbl + (mbase + t0 + tr3)*64 + 32 + cB);
    }
    __syncthreads();
#pragma unroll
    for (int t = 0; t < TT; ++t) {
      float dtv = s_dt[t][dl];
      float uv = (float)*reinterpret_cast<const __bf16*>(&s_up[t][upo])
               + (float)*reinterpret_cast<const __bf16*>(&s_up[t][upo + 16]);
      float cu  = dtv * uv;
      float4 Bv = *reinterpret_cast<const float4*>(&s_b[t][sg]);
      float dA;
      dA = exp2f(dtv * a2[0]); h[0] = dA*h[0] + cu*Bv.x; p[0] *= dA;
      dA = exp2f(dtv * a2[1]); h[1] = dA*h[1] + cu*Bv.y; p[1] *= dA;
      dA = exp2f(dtv * a2[2]); h[2] = dA*h[2] + cu*Bv.z; p[2] *= dA;
      dA = exp2f(dtv * a2[3]); h[3] = dA*h[3] + cu*Bv.w; p[3] *= dA;
    }
    __syncthreads();
  }
  size_t cbase = (((size_t)bi * NC + c) * DI + d) * DSTATE + sg;
  *reinterpret_cast<float4*>(cfF + cbase) = make_float4(h[0],h[1],h[2],h[3]);
  *reinterpret_cast<float4*>(cfP + cbase) = make_float4(p[0],p[1],p[2],p[3]);
}

// ---------------------------------------------------------------------------
// Scan pass 2: serial prefix over NC chunks (final -> entry), in place.
// ---------------------------------------------------------------------------
__global__ __launch_bounds__(256) void chunk_prefix(float* __restrict__ cfF,
                                                    const float* __restrict__ cfP,
                                                    int nb) {
  int gid = blockIdx.x * 256 + threadIdx.x;
  if (gid >= nb * DI * 4) return;
  int bi = gid >> 12;
  int d  = (gid >> 2) & (DI - 1);
  int q  = gid & 3;
  size_t base = (((size_t)bi * NC) * DI + d) * DSTATE + q * 4;
  const size_t cs = (size_t)DI * DSTATE;
  float4 carry = make_float4(0.f, 0.f, 0.f, 0.f);
  for (int c0 = 0; c0 < NC; c0 += 8) {
    float4 f[8], p[8];
#pragma unroll
    for (int i = 0; i < 8; ++i) {
      int c = c0 + i;
      if (c < NC - 1) {
        f[i] = *reinterpret_cast<const float4*>(cfF + base + (size_t)c * cs);
        p[i] = *reinterpret_cast<const float4*>(cfP + base + (size_t)c * cs);
      }
    }
#pragma unroll
    for (int i = 0; i < 8; ++i) {
      int c = c0 + i;
      *reinterpret_cast<float4*>(cfF + base + (size_t)c * cs) = carry;
      if (c < NC - 1) {
        carry.x = p[i].x * carry.x + f[i].x;
        carry.y = p[i].y * carry.y + f[i].y;
        carry.z = p[i].z * carry.z + f[i].z;
        carry.w = p[i].w * carry.w + f[i].w;
      }
    }
  }
}

// ---------------------------------------------------------------------------
// Scan pass 3: scan from entry state + gate; writes packed y in place into uP.
// dt from xz cols [0,1024); z from xz cols [1024,2048).
// ---------------------------------------------------------------------------
__global__ __launch_bounds__(256) void scan_pass3(
    const float* __restrict__ xzp, char* __restrict__ uP,
    const float* __restrict__ dbl,
    const float* __restrict__ Alog, const float* __restrict__ Dp,
    const float* __restrict__ cfF) {
  __shared__ __align__(16) float s_dt[TT][64];
  __shared__ __align__(16) char  s_up[TT][256];
  __shared__ __align__(16) float s_z [TT][64];
  __shared__ __align__(16) float s_bc[TT][32];
  __shared__ __align__(16) float s_y [TT][64];
  int tid = threadIdx.x;
  int d0 = blockIdx.x * 64;
  int c  = blockIdx.y;
  int bi = blockIdx.z;
  int dl = tid >> 2;
  int sg = (tid & 3) * 4;
  int d  = d0 + dl;
  float a2[4], hst[4];
  size_t cbase = (((size_t)bi * NC + c) * DI + d) * DSTATE + sg;
  float4 ent = *reinterpret_cast<const float4*>(cfF + cbase);
  hst[0]=ent.x; hst[1]=ent.y; hst[2]=ent.z; hst[3]=ent.w;
#pragma unroll
  for (int j = 0; j < 4; ++j)
    a2[j] = -expf(Alog[(size_t)d * DSTATE + sg + j]) * 1.44269504088896340736f;
  float dp = Dp[d];
  size_t mbase = (size_t)bi * L_SEQ + (size_t)c * LC;

  int tr = tid >> 4, c4 = (tid & 15) * 4;
  int tr2 = tid >> 3, c2 = (tid & 7) * 4;
  int upo = (dl >> 3) * 32 + (dl & 7) * 2;

  for (int t0 = 0; t0 < LC; t0 += TT) {
    size_t m = mbase + t0 + tr;
    *reinterpret_cast<float4*>(&s_dt[tr][c4]) = *reinterpret_cast<const float4*>(xzp + m*2048 + d0 + c4);
    *reinterpret_cast<float4*>(&s_up[tr][(tid & 15) * 16]) =
        *reinterpret_cast<const float4*>(uP + m * (DI*4) + d0 * 4 + (tid & 15) * 16);
    *reinterpret_cast<float4*>(&s_z [tr][c4]) = *reinterpret_cast<const float4*>(xzp + m*2048 + DI + d0 + c4);
    if (tid < 128) {
      size_t m2 = mbase + t0 + tr2;
      *reinterpret_cast<float4*>(&s_bc[tr2][c2]) = *reinterpret_cast<const float4*>(dbl + m2*64 + 32 + c2);
    }
    __syncthreads();
#pragma unroll
    for (int t = 0; t < TT; ++t) {
      float dtv = s_dt[t][dl];
      float uv = (float)*reinterpret_cast<const __bf16*>(&s_up[t][upo])
               + (float)*reinterpret_cast<const __bf16*>(&s_up[t][upo + 16]);
      float cu  = dtv * uv;
      float4 Bv = *reinterpret_cast<const float4*>(&s_bc[t][sg]);
      float4 Cv = *reinterpret_cast<const float4*>(&s_bc[t][16 + sg]);
      float yp = 0.0f;
      {
        float dA;
        dA = exp2f(dtv * a2[0]); hst[0] = dA*hst[0] + cu*Bv.x; yp += hst[0]*Cv.x;
        dA = exp2f(dtv * a2[1]); hst[1] = dA*hst[1] + cu*Bv.y; yp += hst[1]*Cv.y;
        dA = exp2f(dtv * a2[2]); hst[2] = dA*hst[2] + cu*Bv.z; yp += hst[2]*Cv.z;
        dA = exp2f(dtv * a2[3]); hst[3] = dA*hst[3] + cu*Bv.w; yp += hst[3]*Cv.w;
      }
      yp += __shfl_xor(yp, 1);
      yp += __shfl_xor(yp, 2);
      if ((tid & 3) == 0) {
        float zv = s_z[t][dl];
        s_y[t][dl] = (yp + uv * dp) * (zv / (1.0f + expf(-zv)));
      }
    }
    __syncthreads();
    {
      float4 v = *reinterpret_cast<float4*>(&s_y[tr][c4]);
      int dgl = d0 + c4;
      v4bf hi, lo;
      float f[4] = {v.x, v.y, v.z, v.w};
#pragma unroll
      for (int j = 0; j < 4; ++j) {
        hi[j] = (__bf16)f[j];
        lo[j] = (__bf16)(f[j] - (float)hi[j]);
      }
      char* pp = uP + m * (DI*4) + (dgl >> 3) * 32 + ((dgl & 7) * 2);
      *reinterpret_cast<v4bf*>(pp)      = hi;
      *reinterpret_cast<v4bf*>(pp + 16) = lo;
    }
    __syncthreads();
  }
}

// ---------------------------------------------------------------------------
// Pool (reads fp32 h from final out_proj)
// ---------------------------------------------------------------------------
__global__ __launch_bounds__(512) void pool_kernel(const float* __restrict__ h,
                                                   float* __restrict__ pooled,
                                                   int b0) {
  int b = blockIdx.x >> 5;
  int chunk = blockIdx.x & 31;
  int d = threadIdx.x;
  float s = 0.0f;
  size_t base = (size_t)b * L_SEQ + chunk * 128;
  for (int l = 0; l < 128; ++l) s += h[(base + l) * DM + d];
  atomicAdd(pooled + (size_t)(b0 + b) * DM + d, s * (1.0f / 4096.0f));
}

// ---------------------------------------------------------------------------
// Head: LayerNorm + classifier
// ---------------------------------------------------------------------------
__global__ __launch_bounds__(512) void head_kernel(const float* __restrict__ pooled,
                                                   const float* __restrict__ nw,
                                                   const float* __restrict__ nbv,
                                                   const float* __restrict__ clw,
                                                   const float* __restrict__ clb,
                                                   float* __restrict__ out) {
  __shared__ float rs[8], rq[8];
  __shared__ float ln[512];
  int b = blockIdx.x, tid = threadIdx.x;
  int wid = tid >> 6, lane = tid & 63;
  float v = pooled[(size_t)b * DM + tid];
  float s = v, q = v * v;
#pragma unroll
  for (int off = 1; off < 64; off <<= 1) { s += __shfl_xor(s, off); q += __shfl_xor(q, off); }
  if (lane == 0) { rs[wid] = s; rq[wid] = q; }
  __syncthreads();
  if (tid == 0) {
    float S = 0, Q = 0;
    for (int i = 0; i < 8; ++i) { S += rs[i]; Q += rq[i]; }
    rs[0] = S; rq[0] = Q;
  }
  __syncthreads();
  float mu  = rs[0] / 512.0f;
  float var = rq[0] / 512.0f - mu * mu;
  ln[tid] = (v - mu) * rsqrtf(var + 1e-5f) * nw[tid] + nbv[tid];
  __syncthreads();
  if (tid < 320) {
    int c = tid >> 5, l2 = tid & 31;
    float p = 0.0f;
    for (int dd = l2; dd < 512; dd += 32) p += ln[dd] * clw[c * 512 + dd];
#pragma unroll
    for (int off = 1; off < 32; off <<= 1) p += __shfl_xor(p, off);
    if (l2 == 0) out[(size_t)b * 10 + c] = p + clb[c];
  }
}

// ---------------------------------------------------------------------------
extern "C" void kernel_launch(void* const* d_in, const int* in_sizes, int n_in,
                              void* d_out, int out_size, void* d_ws, size_t ws_size,
                              hipStream_t stream) {
  (void)in_sizes; (void)n_in; (void)out_size;
  const float* x    = (const float*)d_in[0];
  const float* in_w = (const float*)d_in[1];
  const float* in_b = (const float*)d_in[2];
  const float* ipw  = (const float*)d_in[3];
  const float* cw   = (const float*)d_in[4];
  const float* cb   = (const float*)d_in[5];
  const float* xpw  = (const float*)d_in[6];
  const float* dtw  = (const float*)d_in[7];
  const float* dtb  = (const float*)d_in[8];
  const float* Alog = (const float*)d_in[9];
  const float* Dp   = (const float*)d_in[10];
  const float* opw  = (const float*)d_in[11];
  const float* nw   = (const float*)d_in[12];
  const float* nbv  = (const float*)d_in[13];
  const float* clw  = (const float*)d_in[14];
  const float* clb  = (const float*)d_in[15];
  float* out = (float*)d_out;

  // per-token floats: h 512 + xz 2048 (dt aliased into xc half) + uP 1024
  //                 + dbl 64 + hP 512 = 4160
  const size_t per_m_bytes = 4160ull * 4ull;
  const size_t wpack_bytes = (size_t)NLAYERS * (2048*512 + 64*1024 + 512*1024) * 4ull;
  int nb = 16;
  while (nb > 1 &&
         ((size_t)nb * L_SEQ * per_m_bytes
          + (size_t)nb * 2ull * NC * DI * DSTATE * 4ull
          + wpack_bytes + 16 * DM * 4 + 1024) > ws_size)
    nb >>= 1;
  int Mc = nb * L_SEQ;

  char* p = (char*)d_ws;
  float* h      = (float*)p; p += (size_t)Mc * DM   * 4;
  float* xz     = (float*)p; p += (size_t)Mc * 2048 * 4;
  char*  uPb    = p;         p += (size_t)Mc * DI   * 4;
  float* dblb   = (float*)p; p += (size_t)Mc * 64   * 4;
  char*  hP     = p;         p += (size_t)Mc * DM   * 4;
  float* cfF    = (float*)p; p += (size_t)nb * NC * DI * DSTATE * 4;
  float* cfP    = (float*)p; p += (size_t)nb * NC * DI * DSTATE * 4;
  char*  ipwP   = p;         p += (size_t)NLAYERS * 2048 * 512 * 4;
  char*  xpwP   = p;         p += (size_t)NLAYERS * 64 * 1024 * 4;
  char*  opwP   = p;         p += (size_t)NLAYERS * 512 * 1024 * 4;
  float* pooled = (float*)p;

  hipMemsetAsync(pooled, 0, 16 * DM * 4, stream);

  for (int layer = 0; layer < NLAYERS; ++layer) {
    pack_hl<<<(2048*512/8 + 255)/256, 256, 0, stream>>>(
        ipw + (size_t)layer*2048*DM, ipwP + (size_t)layer*2048*512*4, 2048*512/8);
    pack_hl<<<(64*1024/8 + 255)/256, 256, 0, stream>>>(
        xpw + (size_t)layer*64*DI, xpwP + (size_t)layer*64*1024*4, 64*1024/8);
    pack_hl<<<(512*1024/8 + 255)/256, 256, 0, stream>>>(
        opw + (size_t)layer*DM*DI, opwP + (size_t)layer*512*1024*4, 512*1024/8);
  }

  for (int b0 = 0; b0 < 16; b0 += nb) {
    embed_kernel<<<Mc / 4, 256, 0, stream>>>(x, in_w, in_b, hP, b0, Mc);
    for (int layer = 0; layer < NLAYERS; ++layer) {
      const float* cw_l   = cw   + (size_t)layer * DI * 4;
      const float* cb_l   = cb   + (size_t)layer * DI;
      const float* dtw_l  = dtw  + (size_t)layer * DI * 32;
      const float* dtb_l  = dtb  + (size_t)layer * DI;
      const float* Alog_l = Alog + (size_t)layer * DI * DSTATE;
      const float* Dp_l   = Dp   + (size_t)layer * DI;

      gemm_pk3<0><<<dim3(Mc / BM, 2048 / BN), 256, 0, stream>>>(
          hP, ipwP + (size_t)layer*2048*512*4, xz, 512, 512, 2048);
      conv_silu_kernel<<<Mc / 2, 256, 0, stream>>>(xz, cw_l, cb_l, uPb, Mc);
      hipMemsetAsync(dblb, 0, (size_t)Mc * 64 * 4, stream);
      gemm_pk3<1><<<dim3(Mc / BM, 1, 8), 256, 0, stream>>>(
          uPb, xpwP + (size_t)layer*64*1024*4, dblb, 1024, 128, 64);
      dt_tile<<<dim3(Mc / 64, 16), 256, 0, stream>>>(dblb, dtw_l, dtb_l, xz, 2048);
      scan_pass1<<<dim3(16, NC - 1, nb), 256, 0, stream>>>(xz, uPb, dblb, Alog_l, cfF, cfP);
      chunk_prefix<<<(nb * DI * 4 + 255) / 256, 256, 0, stream>>>(cfF, cfP, nb);
      scan_pass3<<<dim3(16, NC, nb), 256, 0, stream>>>(xz, uPb, dblb, Alog_l, Dp_l, cfF);
      gemm_pk3<0><<<dim3(Mc / BM, DM / BN), 256, 0, stream>>>(
          uPb, opwP + (size_t)layer*512*1024*4, h, 1024, 1024, DM);
      if (layer < NLAYERS - 1)
        pack_hl<<<(Mc * DM / 8 + 255)/256, 256, 0, stream>>>(h, hP, Mc * DM / 8);
    }
    pool_kernel<<<nb * 32, 512, 0, stream>>>(h, pooled, b0);
  }
  head_kernel<<<16, 512, 0, stream>>>(pooled, nw, nbv, clw, clb, out);
}

// Round 6
// 10844.110 us; speedup vs baseline: 1.5756x; 1.0325x over previous
//
#include <hip/hip_runtime.h>
#include <hip/hip_bf16.h>
#include <math.h>

#define L_SEQ 4096
#define DM 512
#define DI 1024
#define DSTATE 16
#define NLAYERS 4
#define NC 64         // scan chunks
#define LC 64         // chunk length = L_SEQ / NC
#define TT 16         // timestep tile

typedef __bf16 v8bf __attribute__((ext_vector_type(8)));
typedef __bf16 v4bf __attribute__((ext_vector_type(4)));
typedef float  v4f  __attribute__((ext_vector_type(4)));

static __device__ __forceinline__ v4f mfma16(v8bf a, v8bf b, v4f c) {
  return __builtin_amdgcn_mfma_f32_16x16x32_bf16(a, b, c, 0, 0, 0);
}

// async global->LDS DMA, 16B/lane (LDS dest wave-uniform; HW adds lane*16)
static __device__ __forceinline__ void lds_dma16(const void* g, void* l) {
  __builtin_amdgcn_global_load_lds(
      (const __attribute__((address_space(1))) void*)g,
      (__attribute__((address_space(3))) void*)l, 16, 0, 0);
}

// ---------------------------------------------------------------------------
// Packed hi/lo bf16 ("HL"): per row, kgroup g (8 elems) = 32B: [hi x8][lo x8].
// Row stride K*4 bytes; element d: hi at (d>>3)*32+(d&7)*2, lo at +16.
// ---------------------------------------------------------------------------
__global__ void pack_hl(const float* __restrict__ src, char* __restrict__ dst, int nunits) {
  int i = blockIdx.x * 256 + threadIdx.x;
  if (i >= nunits) return;
  const float4* s = reinterpret_cast<const float4*>(src) + (size_t)i * 2;
  float4 v0 = s[0], v1 = s[1];
  v8bf hi, lo;
  float f[8] = {v0.x, v0.y, v0.z, v0.w, v1.x, v1.y, v1.z, v1.w};
#pragma unroll
  for (int j = 0; j < 8; ++j) {
    hi[j] = (__bf16)f[j];
    lo[j] = (__bf16)(f[j] - (float)hi[j]);
  }
  *reinterpret_cast<v8bf*>(dst + (size_t)i * 32)      = hi;
  *reinterpret_cast<v8bf*>(dst + (size_t)i * 32 + 16) = lo;
}

// ---------------------------------------------------------------------------
// Embed -> packed h only.
// ---------------------------------------------------------------------------
__global__ void embed_kernel(const float* __restrict__ x, const float* __restrict__ in_w,
                             const float* __restrict__ in_b, char* __restrict__ h_pack,
                             int b0, int Mc) {
  int idx = blockIdx.x * 256 + threadIdx.x;   // Mc*64 kgroups
  int g = idx & 63;
  int m = idx >> 6;
  if (m >= Mc) return;
  int d0 = g * 8;
  int bg = b0 + (m >> 12);
  int l  = m & (L_SEQ - 1);
  const float* xp = x + ((size_t)bg * 3) * L_SEQ + l;
  float x0 = xp[0], x1 = xp[L_SEQ], x2 = xp[2 * L_SEQ];
  v8bf hi, lo;
#pragma unroll
  for (int j = 0; j < 8; ++j) {
    int d = d0 + j;
    float f = in_b[d] + x0 * in_w[d*3+0] + x1 * in_w[d*3+1] + x2 * in_w[d*3+2];
    hi[j] = (__bf16)f;
    lo[j] = (__bf16)(f - (float)hi[j]);
  }
  char* pp = h_pack + (size_t)m * (DM * 4) + g * 32;
  *reinterpret_cast<v8bf*>(pp)      = hi;
  *reinterpret_cast<v8bf*>(pp + 16) = lo;
}

// ---------------------------------------------------------------------------
// Split-bf16 3-pass MFMA GEMM, 128x128 tile, BK=32, 4 waves (2x2, each 64x64).
// C[M][N] = A[M][K]*B[N][K]^T on packed HL inputs. LDS 32KB (A 16 + B 16).
// Staging via global_load_lds w=16 with XOR swizzle (unit j of row r at
// position j^(r&7)) done in per-lane GLOBAL addresses.
// Split-K: blockIdx.z slices K into k_len chunks (Kstride = full row K).
// EPI: 0 = fp32 store, 1 = fp32 atomicAdd, 2 = packed-HL store (via LDS).
// ---------------------------------------------------------------------------
template <int EPI>
__global__ __launch_bounds__(256) void gemm128(
    const char* __restrict__ Ap, const char* __restrict__ Bp, void* __restrict__ Cout,
    int Kstride, int k_len, int ldc) {
  __shared__ __align__(16) char lds[32768];
  int tid = threadIdx.x;
  int w = tid >> 6, lane = tid & 63;
  int wm = w & 1, wn = w >> 1;
  int m0 = blockIdx.x * 128, n0 = blockIdx.y * 128;
  size_t Kb = (size_t)Kstride * 4;            // row bytes
  size_t zoff = (size_t)blockIdx.z * k_len * 4;
  int lrow = lane & 15, lq = lane >> 4;

  // staging bases: wave w stages rows w*32..w*32+31; lane l covers row l>>3,
  // swizzled unit (l&7)^((l>>3)&7); inst i adds 8 rows.
  int srow = lane >> 3;
  int sunit = (lane & 7) ^ (srow & 7);
  const char* aBase = Ap + (size_t)(m0 + w * 32 + srow) * Kb + (sunit << 4) + zoff;
  const char* bBase = Bp + (size_t)(n0 + w * 32 + srow) * Kb + (sunit << 4) + zoff;
  char* aLdsW = lds + w * 4096;
  char* bLdsW = lds + 16384 + w * 4096;

  v4f acc[4][4];
#pragma unroll
  for (int i = 0; i < 4; ++i)
#pragma unroll
    for (int j = 0; j < 4; ++j)
#pragma unroll
      for (int e = 0; e < 4; ++e) acc[i][j][e] = 0.0f;

  int aro = (wm * 64 + lrow) * 128;           // A frag row base (LDS)
  int bro = 16384 + (wn * 64 + lrow) * 128;   // B frag row base (LDS)
  int sw = lrow & 7;
  int phi = ((2 * lq)     ^ sw) << 4;
  int plo = ((2 * lq + 1) ^ sw) << 4;

  size_t koff = 0;
  for (int k0 = 0; k0 < k_len; k0 += 32, koff += 128) {
    __syncthreads();
#pragma unroll
    for (int i = 0; i < 4; ++i) lds_dma16(aBase + (size_t)i * 8 * Kb + koff, aLdsW + i * 1024);
#pragma unroll
    for (int i = 0; i < 4; ++i) lds_dma16(bBase + (size_t)i * 8 * Kb + koff, bLdsW + i * 1024);
    __syncthreads();

    v8bf aF[4][2], bF[4][2];
#pragma unroll
    for (int mt = 0; mt < 4; ++mt) {
      const char* pa = lds + aro + mt * 2048;
      aF[mt][0] = *reinterpret_cast<const v8bf*>(pa + phi);
      aF[mt][1] = *reinterpret_cast<const v8bf*>(pa + plo);
    }
#pragma unroll
    for (int nt = 0; nt < 4; ++nt) {
      const char* pb = lds + bro + nt * 2048;
      bF[nt][0] = *reinterpret_cast<const v8bf*>(pb + phi);
      bF[nt][1] = *reinterpret_cast<const v8bf*>(pb + plo);
    }
#pragma unroll
    for (int mt = 0; mt < 4; ++mt)
#pragma unroll
      for (int nt = 0; nt < 4; ++nt) {
        acc[mt][nt] = mfma16(aF[mt][0], bF[nt][0], acc[mt][nt]);  // hi*hi
        acc[mt][nt] = mfma16(aF[mt][0], bF[nt][1], acc[mt][nt]);  // hi*lo
        acc[mt][nt] = mfma16(aF[mt][1], bF[nt][0], acc[mt][nt]);  // lo*hi
      }
  }

  if (EPI == 0 || EPI == 1) {
    float* C = (float*)Cout;
#pragma unroll
    for (int mt = 0; mt < 4; ++mt)
#pragma unroll
      for (int nt = 0; nt < 4; ++nt) {
        int rbase = m0 + wm * 64 + mt * 16 + lq * 4;
        int cidx  = n0 + wn * 64 + nt * 16 + lrow;
#pragma unroll
        for (int r = 0; r < 4; ++r) {
          if (EPI == 0)
            C[(size_t)(rbase + r) * ldc + cidx] = acc[mt][nt][r];
          else
            atomicAdd(&C[(size_t)(rbase + r) * ldc + cidx], acc[mt][nt][r]);
        }
      }
  } else {
    // EPI==2: pack to HL (row stride ldc*4 bytes) via LDS, two 64-col halves.
    char* Cpk = (char*)Cout;
    float* eLds = (float*)lds;
    __syncthreads();   // staging reads done; safe to reuse LDS
#pragma unroll
    for (int h = 0; h < 2; ++h) {
      if (wn == h) {
#pragma unroll
        for (int mt = 0; mt < 4; ++mt)
#pragma unroll
          for (int nt = 0; nt < 4; ++nt)
#pragma unroll
            for (int r = 0; r < 4; ++r)
              eLds[(wm * 64 + mt * 16 + lq * 4 + r) * 64 + nt * 16 + lrow] = acc[mt][nt][r];
      }
      __syncthreads();
#pragma unroll
      for (int t = 0; t < 4; ++t) {
        int idx = tid + t * 256;            // 0..1023
        int row = idx >> 3, g = idx & 7;
        const float* s = eLds + row * 64 + g * 8;
        v8bf hi, lo;
#pragma unroll
        for (int j = 0; j < 8; ++j) {
          float f = s[j];
          hi[j] = (__bf16)f;
          lo[j] = (__bf16)(f - (float)hi[j]);
        }
        char* pp = Cpk + (size_t)(m0 + row) * (ldc * 4) + (((n0 + h * 64) >> 3) + g) * 32;
        *reinterpret_cast<v8bf*>(pp)      = hi;
        *reinterpret_cast<v8bf*>(pp + 16) = lo;
      }
      __syncthreads();
    }
  }
}

// ---------------------------------------------------------------------------
// Depthwise causal conv(k=4) + bias + SiLU -> packed u.
// Thread = 8 tokens x 4 dims (reads 11 rows instead of 4x re-reads).
// ---------------------------------------------------------------------------
__global__ void conv_silu_kernel(const float* __restrict__ xz, const float* __restrict__ cw,
                                 const float* __restrict__ cb,
                                 char* __restrict__ u_pack, int Mc) {
  int idx = blockIdx.x * 256 + threadIdx.x;
  int dg = idx & 255;          // d-group of 4
  int tg = idx >> 8;           // token-group of 8
  if (tg >= (Mc >> 3)) return;
  int d0 = dg * 4;
  int t0 = tg * 8;
  int tloc = t0 & (L_SEQ - 1);
  float4 cwv[4];
#pragma unroll
  for (int j = 0; j < 4; ++j) cwv[j] = *reinterpret_cast<const float4*>(cw + (d0 + j) * 4);
  float4 cb4 = *reinterpret_cast<const float4*>(cb + d0);
  float xv[11][4];
#pragma unroll
  for (int i = 0; i < 11; ++i) {
    if (tloc + i >= 3) {
      float4 v = *reinterpret_cast<const float4*>(xz + (size_t)(t0 - 3 + i) * 2048 + d0);
      xv[i][0] = v.x; xv[i][1] = v.y; xv[i][2] = v.z; xv[i][3] = v.w;
    } else {
      xv[i][0] = xv[i][1] = xv[i][2] = xv[i][3] = 0.0f;
    }
  }
  float cbv[4] = {cb4.x, cb4.y, cb4.z, cb4.w};
#pragma unroll
  for (int tt = 0; tt < 8; ++tt) {
    v4bf hi, lo;
#pragma unroll
    for (int j = 0; j < 4; ++j) {
      float r = cbv[j] + xv[tt][j]     * cwv[j].x + xv[tt + 1][j] * cwv[j].y
                       + xv[tt + 2][j] * cwv[j].z + xv[tt + 3][j] * cwv[j].w;
      r = r / (1.0f + expf(-r));
      hi[j] = (__bf16)r;
      lo[j] = (__bf16)(r - (float)hi[j]);
    }
    char* pp = u_pack + (size_t)(t0 + tt) * (DI * 4) + (d0 >> 3) * 32 + ((d0 & 4) << 1);
    *reinterpret_cast<v4bf*>(pp)      = hi;
    *reinterpret_cast<v4bf*>(pp + 16) = lo;
  }
}

// ---------------------------------------------------------------------------
// dt tile: dt[m][d] = softplus(dbl[m][0:32].dtw[d][:] + dtb[d])
// dbl has ld 128; dt written into the (dead) xc half of xz (ld 2048).
// ---------------------------------------------------------------------------
__global__ __launch_bounds__(256) void dt_tile(const float* __restrict__ dbl,
                                               const float* __restrict__ dtw,
                                               const float* __restrict__ dtb,
                                               float* __restrict__ dt) {
  __shared__ float s_a[64][33];
  __shared__ float s_w[64][33];
  int tid = threadIdx.x;
  int m0 = blockIdx.x * 64, d0 = blockIdx.y * 64;
#pragma unroll
  for (int i = 0; i < 8; ++i) {
    int idx = tid + i * 256;
    int r = idx >> 5, cc = idx & 31;
    s_a[r][cc] = dbl[(size_t)(m0 + r) * 128 + cc];
    s_w[r][cc] = dtw[(size_t)(d0 + r) * 32 + cc];
  }
  __syncthreads();
  int tm = tid >> 4, td = tid & 15;
  float acc[4][4];
#pragma unroll
  for (int i = 0; i < 4; ++i)
#pragma unroll
    for (int j = 0; j < 4; ++j) acc[i][j] = dtb[d0 + td + 16 * j];
#pragma unroll
  for (int k = 0; k < 32; ++k) {
    float a_[4], w_[4];
#pragma unroll
    for (int i = 0; i < 4; ++i) a_[i] = s_a[tm * 4 + i][k];
#pragma unroll
    for (int j = 0; j < 4; ++j) w_[j] = s_w[td + 16 * j][k];
#pragma unroll
    for (int i = 0; i < 4; ++i)
#pragma unroll
      for (int j = 0; j < 4; ++j) acc[i][j] += a_[i] * w_[j];
  }
#pragma unroll
  for (int i = 0; i < 4; ++i)
#pragma unroll
    for (int j = 0; j < 4; ++j) {
      float v = acc[i][j];
      float sp = (v > 15.0f) ? v : log1pf(expf(v));
      dt[(size_t)(m0 + tm * 4 + i) * 2048 + d0 + td + 16 * j] = sp;
    }
}

// ---------------------------------------------------------------------------
// Scan pass 1: per chunk from h=0: final state + decay product. dbl ld 128.
// ---------------------------------------------------------------------------
__global__ __launch_bounds__(256) void scan_pass1(
    const float* __restrict__ xzp, const char* __restrict__ uP,
    const float* __restrict__ dbl, const float* __restrict__ Alog,
    float* __restrict__ cfF, float* __restrict__ cfP) {
  __shared__ __align__(16) float s_dt[TT][64];
  __shared__ __align__(16) char  s_up[TT][256];
  __shared__ __align__(16) float s_b [TT][16];
  int tid = threadIdx.x;
  int d0 = blockIdx.x * 64;
  int c  = blockIdx.y;
  int bi = blockIdx.z;
  int dl = tid >> 2;
  int sg = (tid & 3) * 4;
  int d  = d0 + dl;
  float a2[4], h[4] = {0.f,0.f,0.f,0.f}, p[4] = {1.f,1.f,1.f,1.f};
#pragma unroll
  for (int j = 0; j < 4; ++j)
    a2[j] = -expf(Alog[(size_t)d * DSTATE + sg + j]) * 1.44269504088896340736f;
  size_t mbase = (size_t)bi * L_SEQ + (size_t)c * LC;
  int tr = tid >> 4, c4 = (tid & 15) * 4;
  int upo = (dl >> 3) * 32 + (dl & 7) * 2;

  for (int t0 = 0; t0 < LC; t0 += TT) {
    size_t m = mbase + t0 + tr;
    *reinterpret_cast<float4*>(&s_dt[tr][c4]) = *reinterpret_cast<const float4*>(xzp + m*2048 + d0 + c4);
    *reinterpret_cast<float4*>(&s_up[tr][(tid & 15) * 16]) =
        *reinterpret_cast<const float4*>(uP + m * (DI*4) + d0 * 4 + (tid & 15) * 16);
    if (tid < 64) {
      int tr3 = tid >> 2, cB = (tid & 3) * 4;
      *reinterpret_cast<float4*>(&s_b[tr3][cB]) =
          *reinterpret_cast<const float4*>(dbl + (mbase + t0 + tr3)*128 + 32 + cB);
    }
    __syncthreads();
#pragma unroll
    for (int t = 0; t < TT; ++t) {
      float dtv = s_dt[t][dl];
      float uv = (float)*reinterpret_cast<const __bf16*>(&s_up[t][upo])
               + (float)*reinterpret_cast<const __bf16*>(&s_up[t][upo + 16]);
      float cu  = dtv * uv;
      float4 Bv = *reinterpret_cast<const float4*>(&s_b[t][sg]);
      float dA;
      dA = exp2f(dtv * a2[0]); h[0] = dA*h[0] + cu*Bv.x; p[0] *= dA;
      dA = exp2f(dtv * a2[1]); h[1] = dA*h[1] + cu*Bv.y; p[1] *= dA;
      dA = exp2f(dtv * a2[2]); h[2] = dA*h[2] + cu*Bv.z; p[2] *= dA;
      dA = exp2f(dtv * a2[3]); h[3] = dA*h[3] + cu*Bv.w; p[3] *= dA;
    }
    __syncthreads();
  }
  size_t cbase = (((size_t)bi * NC + c) * DI + d) * DSTATE + sg;
  *reinterpret_cast<float4*>(cfF + cbase) = make_float4(h[0],h[1],h[2],h[3]);
  *reinterpret_cast<float4*>(cfP + cbase) = make_float4(p[0],p[1],p[2],p[3]);
}

// ---------------------------------------------------------------------------
// Scan pass 2: serial prefix over NC chunks (final -> entry), in place.
// ---------------------------------------------------------------------------
__global__ __launch_bounds__(256) void chunk_prefix(float* __restrict__ cfF,
                                                    const float* __restrict__ cfP,
                                                    int nb) {
  int gid = blockIdx.x * 256 + threadIdx.x;
  if (gid >= nb * DI * 4) return;
  int bi = gid >> 12;
  int d  = (gid >> 2) & (DI - 1);
  int q  = gid & 3;
  size_t base = (((size_t)bi * NC) * DI + d) * DSTATE + q * 4;
  const size_t cs = (size_t)DI * DSTATE;
  float4 carry = make_float4(0.f, 0.f, 0.f, 0.f);
  for (int c0 = 0; c0 < NC; c0 += 8) {
    float4 f[8], p[8];
#pragma unroll
    for (int i = 0; i < 8; ++i) {
      int c = c0 + i;
      if (c < NC - 1) {
        f[i] = *reinterpret_cast<const float4*>(cfF + base + (size_t)c * cs);
        p[i] = *reinterpret_cast<const float4*>(cfP + base + (size_t)c * cs);
      }
    }
#pragma unroll
    for (int i = 0; i < 8; ++i) {
      int c = c0 + i;
      *reinterpret_cast<float4*>(cfF + base + (size_t)c * cs) = carry;
      if (c < NC - 1) {
        carry.x = p[i].x * carry.x + f[i].x;
        carry.y = p[i].y * carry.y + f[i].y;
        carry.z = p[i].z * carry.z + f[i].z;
        carry.w = p[i].w * carry.w + f[i].w;
      }
    }
  }
}

// ---------------------------------------------------------------------------
// Scan pass 3: scan from entry state + gate; writes packed y in place into uP.
// ---------------------------------------------------------------------------
__global__ __launch_bounds__(256) void scan_pass3(
    const float* __restrict__ xzp, char* __restrict__ uP,
    const float* __restrict__ dbl,
    const float* __restrict__ Alog, const float* __restrict__ Dp,
    const float* __restrict__ cfF) {
  __shared__ __align__(16) float s_dt[TT][64];
  __shared__ __align__(16) char  s_up[TT][256];
  __shared__ __align__(16) float s_z [TT][64];
  __shared__ __align__(16) float s_bc[TT][32];
  __shared__ __align__(16) float s_y [TT][64];
  int tid = threadIdx.x;
  int d0 = blockIdx.x * 64;
  int c  = blockIdx.y;
  int bi = blockIdx.z;
  int dl = tid >> 2;
  int sg = (tid & 3) * 4;
  int d  = d0 + dl;
  float a2[4], hst[4];
  size_t cbase = (((size_t)bi * NC + c) * DI + d) * DSTATE + sg;
  float4 ent = *reinterpret_cast<const float4*>(cfF + cbase);
  hst[0]=ent.x; hst[1]=ent.y; hst[2]=ent.z; hst[3]=ent.w;
#pragma unroll
  for (int j = 0; j < 4; ++j)
    a2[j] = -expf(Alog[(size_t)d * DSTATE + sg + j]) * 1.44269504088896340736f;
  float dp = Dp[d];
  size_t mbase = (size_t)bi * L_SEQ + (size_t)c * LC;

  int tr = tid >> 4, c4 = (tid & 15) * 4;
  int tr2 = tid >> 3, c2 = (tid & 7) * 4;
  int upo = (dl >> 3) * 32 + (dl & 7) * 2;

  for (int t0 = 0; t0 < LC; t0 += TT) {
    size_t m = mbase + t0 + tr;
    *reinterpret_cast<float4*>(&s_dt[tr][c4]) = *reinterpret_cast<const float4*>(xzp + m*2048 + d0 + c4);
    *reinterpret_cast<float4*>(&s_up[tr][(tid & 15) * 16]) =
        *reinterpret_cast<const float4*>(uP + m * (DI*4) + d0 * 4 + (tid & 15) * 16);
    *reinterpret_cast<float4*>(&s_z [tr][c4]) = *reinterpret_cast<const float4*>(xzp + m*2048 + DI + d0 + c4);
    if (tid < 128) {
      size_t m2 = mbase + t0 + tr2;
      *reinterpret_cast<float4*>(&s_bc[tr2][c2]) = *reinterpret_cast<const float4*>(dbl + m2*128 + 32 + c2);
    }
    __syncthreads();
#pragma unroll
    for (int t = 0; t < TT; ++t) {
      float dtv = s_dt[t][dl];
      float uv = (float)*reinterpret_cast<const __bf16*>(&s_up[t][upo])
               + (float)*reinterpret_cast<const __bf16*>(&s_up[t][upo + 16]);
      float cu  = dtv * uv;
      float4 Bv = *reinterpret_cast<const float4*>(&s_bc[t][sg]);
      float4 Cv = *reinterpret_cast<const float4*>(&s_bc[t][16 + sg]);
      float yp = 0.0f;
      {
        float dA;
        dA = exp2f(dtv * a2[0]); hst[0] = dA*hst[0] + cu*Bv.x; yp += hst[0]*Cv.x;
        dA = exp2f(dtv * a2[1]); hst[1] = dA*hst[1] + cu*Bv.y; yp += hst[1]*Cv.y;
        dA = exp2f(dtv * a2[2]); hst[2] = dA*hst[2] + cu*Bv.z; yp += hst[2]*Cv.z;
        dA = exp2f(dtv * a2[3]); hst[3] = dA*hst[3] + cu*Bv.w; yp += hst[3]*Cv.w;
      }
      yp += __shfl_xor(yp, 1);
      yp += __shfl_xor(yp, 2);
      if ((tid & 3) == 0) {
        float zv = s_z[t][dl];
        s_y[t][dl] = (yp + uv * dp) * (zv / (1.0f + expf(-zv)));
      }
    }
    __syncthreads();
    {
      float4 v = *reinterpret_cast<float4*>(&s_y[tr][c4]);
      int dgl = d0 + c4;
      v4bf hi, lo;
      float f[4] = {v.x, v.y, v.z, v.w};
#pragma unroll
      for (int j = 0; j < 4; ++j) {
        hi[j] = (__bf16)f[j];
        lo[j] = (__bf16)(f[j] - (float)hi[j]);
      }
      char* pp = uP + m * (DI*4) + (dgl >> 3) * 32 + ((dgl & 7) * 2);
      *reinterpret_cast<v4bf*>(pp)      = hi;
      *reinterpret_cast<v4bf*>(pp + 16) = lo;
    }
    __syncthreads();
  }
}

// ---------------------------------------------------------------------------
// Pool: reads packed HL h (hi+lo), accumulates mean.
// ---------------------------------------------------------------------------
__global__ __launch_bounds__(512) void pool_kernel(const char* __restrict__ hP,
                                                   float* __restrict__ pooled,
                                                   int b0) {
  int b = blockIdx.x >> 5;
  int chunk = blockIdx.x & 31;
  int d = threadIdx.x;
  int off = (d >> 3) * 32 + (d & 7) * 2;
  float s = 0.0f;
  size_t base = (size_t)b * L_SEQ + chunk * 128;
  for (int l = 0; l < 128; ++l) {
    const char* p = hP + (base + l) * (DM * 4) + off;
    s += (float)*reinterpret_cast<const __bf16*>(p)
       + (float)*reinterpret_cast<const __bf16*>(p + 16);
  }
  atomicAdd(pooled + (size_t)(b0 + b) * DM + d, s * (1.0f / 4096.0f));
}

// ---------------------------------------------------------------------------
// Head: LayerNorm + classifier
// ---------------------------------------------------------------------------
__global__ __launch_bounds__(512) void head_kernel(const float* __restrict__ pooled,
                                                   const float* __restrict__ nw,
                                                   const float* __restrict__ nbv,
                                                   const float* __restrict__ clw,
                                                   const float* __restrict__ clb,
                                                   float* __restrict__ out) {
  __shared__ float rs[8], rq[8];
  __shared__ float ln[512];
  int b = blockIdx.x, tid = threadIdx.x;
  int wid = tid >> 6, lane = tid & 63;
  float v = pooled[(size_t)b * DM + tid];
  float s = v, q = v * v;
#pragma unroll
  for (int off = 1; off < 64; off <<= 1) { s += __shfl_xor(s, off); q += __shfl_xor(q, off); }
  if (lane == 0) { rs[wid] = s; rq[wid] = q; }
  __syncthreads();
  if (tid == 0) {
    float S = 0, Q = 0;
    for (int i = 0; i < 8; ++i) { S += rs[i]; Q += rq[i]; }
    rs[0] = S; rq[0] = Q;
  }
  __syncthreads();
  float mu  = rs[0] / 512.0f;
  float var = rq[0] / 512.0f - mu * mu;
  ln[tid] = (v - mu) * rsqrtf(var + 1e-5f) * nw[tid] + nbv[tid];
  __syncthreads();
  if (tid < 320) {
    int c = tid >> 5, l2 = tid & 31;
    float p = 0.0f;
    for (int dd = l2; dd < 512; dd += 32) p += ln[dd] * clw[c * 512 + dd];
#pragma unroll
    for (int off = 1; off < 32; off <<= 1) p += __shfl_xor(p, off);
    if (l2 == 0) out[(size_t)b * 10 + c] = p + clb[c];
  }
}

// ---------------------------------------------------------------------------
extern "C" void kernel_launch(void* const* d_in, const int* in_sizes, int n_in,
                              void* d_out, int out_size, void* d_ws, size_t ws_size,
                              hipStream_t stream) {
  (void)in_sizes; (void)n_in; (void)out_size;
  const float* x    = (const float*)d_in[0];
  const float* in_w = (const float*)d_in[1];
  const float* in_b = (const float*)d_in[2];
  const float* ipw  = (const float*)d_in[3];
  const float* cw   = (const float*)d_in[4];
  const float* cb   = (const float*)d_in[5];
  const float* xpw  = (const float*)d_in[6];
  const float* dtw  = (const float*)d_in[7];
  const float* dtb  = (const float*)d_in[8];
  const float* Alog = (const float*)d_in[9];
  const float* Dp   = (const float*)d_in[10];
  const float* opw  = (const float*)d_in[11];
  const float* nw   = (const float*)d_in[12];
  const float* nbv  = (const float*)d_in[13];
  const float* clw  = (const float*)d_in[14];
  const float* clb  = (const float*)d_in[15];
  float* out = (float*)d_out;

  // per-token floats: xz 2048 (dt aliased into xc half) + uP 1024 + dbl 128 + hP 512 = 3712
  const size_t per_m_bytes = 3712ull * 4ull;
  const size_t wpack_bytes = (size_t)NLAYERS * (2048*512 + 64*1024 + 512*1024) * 4ull;
  int nb = 16;
  while (nb > 1 &&
         ((size_t)nb * L_SEQ * per_m_bytes
          + (size_t)nb * 2ull * NC * DI * DSTATE * 4ull
          + wpack_bytes + 16 * DM * 4 + 1024) > ws_size)
    nb >>= 1;
  int Mc = nb * L_SEQ;

  char* p = (char*)d_ws;
  float* xz     = (float*)p; p += (size_t)Mc * 2048 * 4;
  char*  uPb    = p;         p += (size_t)Mc * DI   * 4;
  float* dblb   = (float*)p; p += (size_t)Mc * 128  * 4;
  char*  hP     = p;         p += (size_t)Mc * DM   * 4;
  float* cfF    = (float*)p; p += (size_t)nb * NC * DI * DSTATE * 4;
  float* cfP    = (float*)p; p += (size_t)nb * NC * DI * DSTATE * 4;
  char*  ipwP   = p;         p += (size_t)NLAYERS * 2048 * 512 * 4;
  char*  xpwP   = p;         p += (size_t)NLAYERS * 64 * 1024 * 4;
  char*  opwP   = p;         p += (size_t)NLAYERS * 512 * 1024 * 4;
  float* pooled = (float*)p;

  hipMemsetAsync(pooled, 0, 16 * DM * 4, stream);

  for (int layer = 0; layer < NLAYERS; ++layer) {
    pack_hl<<<(2048*512/8 + 255)/256, 256, 0, stream>>>(
        ipw + (size_t)layer*2048*DM, ipwP + (size_t)layer*2048*512*4, 2048*512/8);
    pack_hl<<<(64*1024/8 + 255)/256, 256, 0, stream>>>(
        xpw + (size_t)layer*64*DI, xpwP + (size_t)layer*64*1024*4, 64*1024/8);
    pack_hl<<<(512*1024/8 + 255)/256, 256, 0, stream>>>(
        opw + (size_t)layer*DM*DI, opwP + (size_t)layer*512*1024*4, 512*1024/8);
  }

  for (int b0 = 0; b0 < 16; b0 += nb) {
    embed_kernel<<<Mc / 4, 256, 0, stream>>>(x, in_w, in_b, hP, b0, Mc);
    for (int layer = 0; layer < NLAYERS; ++layer) {
      const float* cw_l   = cw   + (size_t)layer * DI * 4;
      const float* cb_l   = cb   + (size_t)layer * DI;
      const float* dtw_l  = dtw  + (size_t)layer * DI * 32;
      const float* dtb_l  = dtb  + (size_t)layer * DI;
      const float* Alog_l = Alog + (size_t)layer * DI * DSTATE;
      const float* Dp_l   = Dp   + (size_t)layer * DI;

      gemm128<0><<<dim3(Mc / 128, 2048 / 128), 256, 0, stream>>>(
          hP, ipwP + (size_t)layer*2048*512*4, xz, 512, 512, 2048);
      conv_silu_kernel<<<Mc / 8, 256, 0, stream>>>(xz, cw_l, cb_l, uPb, Mc);
      hipMemsetAsync(dblb, 0, (size_t)Mc * 128 * 4, stream);
      gemm128<1><<<dim3(Mc / 128, 1, 8), 256, 0, stream>>>(
          uPb, xpwP + (size_t)layer*64*1024*4, dblb, 1024, 128, 128);
      dt_tile<<<dim3(Mc / 64, 16), 256, 0, stream>>>(dblb, dtw_l, dtb_l, xz);
      scan_pass1<<<dim3(16, NC - 1, nb), 256, 0, stream>>>(xz, uPb, dblb, Alog_l, cfF, cfP);
      chunk_prefix<<<(nb * DI * 4 + 255) / 256, 256, 0, stream>>>(cfF, cfP, nb);
      scan_pass3<<<dim3(16, NC, nb), 256, 0, stream>>>(xz, uPb, dblb, Alog_l, Dp_l, cfF);
      gemm128<2><<<dim3(Mc / 128, DM / 128), 256, 0, stream>>>(
          uPb, opwP + (size_t)layer*512*1024*4, hP, 1024, 1024, 512);
    }
    pool_kernel<<<nb * 32, 512, 0, stream>>>(hP, pooled, b0);
  }
  head_kernel<<<16, 512, 0, stream>>>(pooled, nw, nbv, clw, clb, out);
}